// Round 1
// baseline (1837.815 us; speedup 1.0000x reference)
//
#include <hip/hip_runtime.h>
#include <math.h>

// ---------------- constants ----------------
#define FH 200
#define FW 200
#define HW 40000            // FH*FW
#define C_IN 256
#define NUM_A 9
#define NANCH 360000        // HW*NUM_A
#define PRE_K 2000
#define OUT_K 1000
#define IMG_SZ 1600.0f
#define MIN_SZ 16.0f
#define NMS_TH 0.7f
#define BBOX_CLIP_F 4.135166556742356f   // log(1000/16)

// ---------------- workspace layout (bytes) ----------------
#define OFF_X      ((size_t)0)                      // 256*40000 f = 40,960,000
#define OFF_PROP   ((size_t)40960000)               // 360000*4 f  = 5,760,000
#define OFF_SCORE  ((size_t)46720000)               // 360000 f    = 1,440,000
#define OFF_HIST   ((size_t)48160000)               // 256 u32     = 1,024
#define OFF_STATE  ((size_t)48161024)               // 16 u32      = 64
#define OFF_CAND   ((size_t)48161088)               // 4096 u64    = 32,768
#define OFF_BOXS   ((size_t)48193856)               // 2000*4 f    = 32,000
#define OFF_SCS    ((size_t)48225856)               // 2000 f      = 8,000
#define OFF_MASK   ((size_t)48233856)               // 2000*32 u64 = 512,000

// =====================================================================
// Kernel 1: 3x3 conv + bias + ReLU.  x[co][h*200+w]
// Block: 256 thr = 16(tx: 4px each) x 16(ty: 4co each). Tile 64co x 64px.
// Grid: (4 px-segs, 200 rows, 4 co-tiles)
// =====================================================================
#define CONV_CI 8
__global__ __launch_bounds__(256) void conv3x3_relu(
    const float* __restrict__ feat, const float* __restrict__ w,
    const float* __restrict__ b, float* __restrict__ x) {
  __shared__ float wlds[CONV_CI * 64 * 12];  // [ci][co][12] (taps 0..8, pad 12)
  __shared__ float flds[CONV_CI * 3 * 68];   // [ci][row][68] (cols 0..65)
  const int t = threadIdx.x;
  const int tx = t & 15, ty = t >> 4;
  const int px0 = blockIdx.x * 64;
  const int h = blockIdx.y;
  const int co0 = blockIdx.z * 64;

  float acc[4][4];
#pragma unroll
  for (int i = 0; i < 4; ++i)
#pragma unroll
    for (int j = 0; j < 4; ++j) acc[i][j] = 0.f;

  for (int ci0 = 0; ci0 < C_IN; ci0 += CONV_CI) {
    __syncthreads();
    // stage weights: 64co x 8ci x 9tap
    for (int e = t; e < 64 * CONV_CI * 9; e += 256) {
      int co = e / (CONV_CI * 9);
      int r = e % (CONV_CI * 9);
      int ci = r / 9, tap = r % 9;
      wlds[(ci * 64 + co) * 12 + tap] =
          w[(size_t)(co0 + co) * 2304 + (size_t)ci0 * 9 + r];
    }
    // stage feat: 8ci x 3rows x 66cols  (halo, zero-padded)
    for (int e = t; e < CONV_CI * 3 * 66; e += 256) {
      int ci = e / 198;
      int rr = (e % 198) / 66;
      int col = e % 66;
      int hh = h - 1 + rr;
      int ww = px0 - 1 + col;
      float v = 0.f;
      if ((unsigned)hh < (unsigned)FH && (unsigned)ww < (unsigned)FW)
        v = feat[(size_t)(ci0 + ci) * HW + hh * FW + ww];
      flds[(ci * 3 + rr) * 68 + col] = v;
    }
    __syncthreads();
#pragma unroll
    for (int ci = 0; ci < CONV_CI; ++ci) {
      float f[3][6];
#pragma unroll
      for (int r = 0; r < 3; ++r)
#pragma unroll
        for (int j = 0; j < 6; ++j)
          f[r][j] = flds[(ci * 3 + r) * 68 + tx * 4 + j];
      float wv[4][9];
#pragma unroll
      for (int cc = 0; cc < 4; ++cc) {
        const float* wp = &wlds[(ci * 64 + ty * 4 + cc) * 12];
#pragma unroll
        for (int tap = 0; tap < 9; ++tap) wv[cc][tap] = wp[tap];
      }
#pragma unroll
      for (int kh = 0; kh < 3; ++kh)
#pragma unroll
        for (int kw = 0; kw < 3; ++kw)
#pragma unroll
          for (int cc = 0; cc < 4; ++cc)
#pragma unroll
            for (int p = 0; p < 4; ++p)
              acc[cc][p] = fmaf(wv[cc][kh * 3 + kw], f[kh][p + kw], acc[cc][p]);
    }
  }
  int pw0 = px0 + tx * 4;
  if (pw0 < FW) {
#pragma unroll
    for (int cc = 0; cc < 4; ++cc) {
      int co = co0 + ty * 4 + cc;
      float bias = b[co];
      float4 v;
      v.x = fmaxf(acc[cc][0] + bias, 0.f);
      v.y = fmaxf(acc[cc][1] + bias, 0.f);
      v.z = fmaxf(acc[cc][2] + bias, 0.f);
      v.w = fmaxf(acc[cc][3] + bias, 0.f);
      *(float4*)(x + (size_t)co * HW + h * FW + pw0) = v;
    }
  }
}

// =====================================================================
// Kernel 2: fused 1x1 heads + anchors + deltas + sigmoid
// =====================================================================
__device__ __forceinline__ void emit_px(int px, const float (&A)[48],
                                        const float* __restrict__ cls_b,
                                        const float* __restrict__ reg_b,
                                        float* __restrict__ prop,
                                        float* __restrict__ score) {
  const float scv[3] = {128.f, 256.f, 512.f};
  const float arv[3] = {0.5f, 1.f, 2.f};
  float sx = (float)(px % FW) * 8.0f;
  float sy = (float)(px / FW) * 8.0f;
#pragma unroll
  for (int a = 0; a < NUM_A; ++a) {
    int ai = a / 3, si = a % 3;
    float hr = sqrtf(arv[ai]);
    float wr = 1.0f / hr;
    float wsz = wr * scv[si];
    float hsz = hr * scv[si];
    float rw = nearbyintf(wsz * 0.5f);   // round-half-even, matches np.round
    float rh = nearbyintf(hsz * 0.5f);
    float ax0 = sx - rw, ay0 = sy - rh, ax1 = sx + rw, ay1 = sy + rh;
    float aw = ax1 - ax0, ah = ay1 - ay0;
    float cx = ax0 + 0.5f * aw, cy = ay0 + 0.5f * ah;
    float dx = A[9 + a * 4 + 0] + reg_b[a * 4 + 0];
    float dy = A[9 + a * 4 + 1] + reg_b[a * 4 + 1];
    float dw = fminf(A[9 + a * 4 + 2] + reg_b[a * 4 + 2], BBOX_CLIP_F);
    float dh = fminf(A[9 + a * 4 + 3] + reg_b[a * 4 + 3], BBOX_CLIP_F);
    float pcx = dx * aw + cx;
    float pcy = dy * ah + cy;
    float pw = expf(dw) * aw;
    float ph = expf(dh) * ah;
    size_t base = (size_t)(px * NUM_A + a) * 4;
    prop[base + 0] = pcx - 0.5f * pw;
    prop[base + 1] = pcy - 0.5f * ph;
    prop[base + 2] = pcx + 0.5f * pw;
    prop[base + 3] = pcy + 0.5f * ph;
    float lg = A[a] + cls_b[a];
    score[px * NUM_A + a] = 1.0f / (1.0f + expf(-lg));
  }
}

__global__ __launch_bounds__(256) void heads_kernel(
    const float* __restrict__ x, const float* __restrict__ cls_w,
    const float* __restrict__ cls_b, const float* __restrict__ reg_w,
    const float* __restrict__ reg_b, float* __restrict__ prop,
    float* __restrict__ score) {
  __shared__ float wl[256 * 48];  // [c][k], k: 0..8 cls, 9..44 reg, 45..47 zero
  int t = threadIdx.x;
  for (int e = t; e < 256 * 48; e += 256) {
    int c = e / 48, k = e % 48;
    float v = 0.f;
    if (k < 9) v = cls_w[k * 256 + c];
    else if (k < 45) v = reg_w[(k - 9) * 256 + c];
    wl[e] = v;
  }
  __syncthreads();
  int tid = blockIdx.x * 256 + t;
  int px0 = tid * 2;
  if (px0 >= HW) return;
  float a0[48], a1[48];
#pragma unroll
  for (int k = 0; k < 48; ++k) { a0[k] = 0.f; a1[k] = 0.f; }
  for (int c = 0; c < 256; ++c) {
    float2 xv = *(const float2*)(x + (size_t)c * HW + px0);
    const float* wp = &wl[c * 48];
#pragma unroll
    for (int kk = 0; kk < 12; ++kk) {
      float4 w4 = *(const float4*)(wp + kk * 4);
      a0[kk * 4 + 0] += xv.x * w4.x;  a1[kk * 4 + 0] += xv.y * w4.x;
      a0[kk * 4 + 1] += xv.x * w4.y;  a1[kk * 4 + 1] += xv.y * w4.y;
      a0[kk * 4 + 2] += xv.x * w4.z;  a1[kk * 4 + 2] += xv.y * w4.z;
      a0[kk * 4 + 3] += xv.x * w4.w;  a1[kk * 4 + 3] += xv.y * w4.w;
    }
  }
  emit_px(px0, a0, cls_b, reg_b, prop, score);
  emit_px(px0 + 1, a1, cls_b, reg_b, prop, score);
}

// =====================================================================
// Radix select (4 passes of 8 bits) for exact top-2000 threshold
// key = float bits of sigmoid score (all positive -> monotonic)
// =====================================================================
__global__ __launch_bounds__(256) void hist_kernel(
    const float* __restrict__ score, unsigned int* __restrict__ hist,
    const unsigned int* __restrict__ state, int pass) {
  __shared__ unsigned int h[256];
  int t = threadIdx.x;
  h[t] = 0;
  __syncthreads();
  unsigned int prefix = (pass == 0) ? 0u : state[0];
  int shift = 24 - 8 * pass;
  for (int i = blockIdx.x * 256 + t; i < NANCH; i += gridDim.x * 256) {
    unsigned int key = __float_as_uint(score[i]);
    bool m = (pass == 0) || ((key >> (32 - 8 * pass)) == prefix);
    if (m) atomicAdd(&h[(key >> shift) & 255u], 1u);
  }
  __syncthreads();
  if (h[t]) atomicAdd(&hist[t], h[t]);
}

__global__ __launch_bounds__(256) void scan_kernel(
    unsigned int* __restrict__ hist, unsigned int* __restrict__ state, int pass) {
  __shared__ unsigned int s0[256], s1[256];
  int t = threadIdx.x;
  unsigned int hv = hist[t];
  hist[t] = 0u;  // pre-zero for next pass
  s0[t] = hv;
  __syncthreads();
  unsigned int* A = s0;
  unsigned int* B = s1;
  for (int off = 1; off < 256; off <<= 1) {
    B[t] = A[t] + ((t + off < 256) ? A[t + off] : 0u);
    __syncthreads();
    unsigned int* tmp = A; A = B; B = tmp;
  }
  // A[t] = inclusive suffix sum (count of keys with byte >= t)
  unsigned int prefix = (pass == 0) ? 0u : state[0];
  unsigned int rem = (pass == 0) ? (unsigned)PRE_K : state[1];
  unsigned int suf = A[t];
  unsigned int sufn = (t < 255) ? A[t + 1] : 0u;
  if (suf >= rem && sufn < rem) {
    state[0] = (prefix << 8) | (unsigned int)t;
    state[1] = rem - sufn;
  }
}

__global__ __launch_bounds__(256) void collect_kernel(
    const float* __restrict__ score, unsigned int* __restrict__ state,
    unsigned long long* __restrict__ cand) {
  unsigned int T = state[0];
  for (int i = blockIdx.x * 256 + threadIdx.x; i < NANCH; i += gridDim.x * 256) {
    unsigned int key = __float_as_uint(score[i]);
    if (key >= T) {
      unsigned int pos = atomicAdd(&state[4], 1u);
      if (pos < 4096u)
        cand[pos] = ((unsigned long long)key << 32) |
                    (unsigned long long)(~(unsigned int)i);
    }
  }
}

// =====================================================================
// Bitonic sort (desc by key, ties asc by index) + gather + clip + valid
// + stable partition (valid first, both order-preserving)
// =====================================================================
__global__ __launch_bounds__(1024) void sort_gather(
    const unsigned long long* __restrict__ cand,
    const unsigned int* __restrict__ state, const float* __restrict__ prop,
    const float* __restrict__ score, float* __restrict__ boxes_s,
    float* __restrict__ sc_s) {
  __shared__ unsigned long long sk[4096];
  int t = threadIdx.x;
  unsigned int cnt = state[4];
  if (cnt > 4096u) cnt = 4096u;
  for (int e = t; e < 4096; e += 1024) sk[e] = (e < (int)cnt) ? cand[e] : 0ull;
  __syncthreads();
  for (int k = 2; k <= 4096; k <<= 1) {
    for (int j = k >> 1; j > 0; j >>= 1) {
      for (int i = t; i < 4096; i += 1024) {
        int l = i ^ j;
        if (l > i) {
          unsigned long long a = sk[i], bb = sk[l];
          bool up = ((i & k) == 0);
          bool sw = up ? (a < bb) : (a > bb);  // descending overall
          if (sw) { sk[i] = bb; sk[l] = a; }
        }
      }
      __syncthreads();
    }
  }
  // gather first 2000 into registers
  float bx[2][4];
  float sc2[2] = {-1.f, -1.f};
  bool valid2[2] = {false, false};
#pragma unroll
  for (int s = 0; s < 2; ++s) {
    int i = t + s * 1024;
    bx[s][0] = bx[s][1] = bx[s][2] = bx[s][3] = 0.f;
    if (i < PRE_K) {
      unsigned long long v = sk[i];
      unsigned int idx = ~(unsigned int)(v & 0xFFFFFFFFull);
      float4 p = *(const float4*)(prop + (size_t)idx * 4);
      float x0 = fminf(fmaxf(p.x, 0.f), IMG_SZ);
      float y0 = fminf(fmaxf(p.y, 0.f), IMG_SZ);
      float x1 = fminf(fmaxf(p.z, 0.f), IMG_SZ);
      float y1 = fminf(fmaxf(p.w, 0.f), IMG_SZ);
      bool valid = (x1 - x0 >= MIN_SZ) && (y1 - y0 >= MIN_SZ);
      bx[s][0] = x0; bx[s][1] = y0; bx[s][2] = x1; bx[s][3] = y1;
      valid2[s] = valid;
      sc2[s] = valid ? score[idx] : -1.0f;
    }
  }
  __syncthreads();
  // stable partition: valid (order kept) then invalid (order kept)
  int* A = (int*)sk;
  int* B = A + 2048;
#pragma unroll
  for (int s = 0; s < 2; ++s) {
    int i = t + s * 1024;
    A[i] = (i < PRE_K && valid2[s]) ? 1 : 0;
  }
  __syncthreads();
  for (int off = 1; off < 2048; off <<= 1) {
#pragma unroll
    for (int s = 0; s < 2; ++s) {
      int i = t + s * 1024;
      B[i] = A[i] + ((i >= off) ? A[i - off] : 0);
    }
    __syncthreads();
    int* tmp = A; A = B; B = tmp;
  }
  int total = A[2047];
#pragma unroll
  for (int s = 0; s < 2; ++s) {
    int i = t + s * 1024;
    if (i < PRE_K) {
      int inc = A[i];
      int pos = valid2[s] ? (inc - 1) : (total + (i - inc));
      boxes_s[pos * 4 + 0] = bx[s][0];
      boxes_s[pos * 4 + 1] = bx[s][1];
      boxes_s[pos * 4 + 2] = bx[s][2];
      boxes_s[pos * 4 + 3] = bx[s][3];
      sc_s[pos] = sc2[s];
    }
  }
}

// =====================================================================
// IoU suppression bitmask: mask[i][wj] bit k  <=>  j=wj*64+k, j>i, IoU>0.7
// =====================================================================
__global__ __launch_bounds__(64) void iou_kernel(
    const float* __restrict__ boxes_s, unsigned long long* __restrict__ mask) {
  int bi = blockIdx.y, bj = blockIdx.x;
  int t = threadIdx.x;
  __shared__ float4 cb[64];
  int jc = bj * 64 + t;
  float4 z; z.x = z.y = z.z = z.w = 0.f;
  cb[t] = (jc < PRE_K) ? *(const float4*)(boxes_s + (size_t)jc * 4) : z;
  __syncthreads();
  int i = bi * 64 + t;
  if (i >= PRE_K) return;
  float4 a = *(const float4*)(boxes_s + (size_t)i * 4);
  float areaA = (a.z - a.x) * (a.w - a.y);
  unsigned long long bits = 0ull;
  for (int jj = 0; jj < 64; ++jj) {
    int j = bj * 64 + jj;
    if (j < PRE_K && j > i) {
      float4 b = cb[jj];
      float areaB = (b.z - b.x) * (b.w - b.y);
      float ltx = fmaxf(a.x, b.x), lty = fmaxf(a.y, b.y);
      float rbx = fminf(a.z, b.z), rby = fminf(a.w, b.w);
      float w = fmaxf(rbx - ltx, 0.f), h = fmaxf(rby - lty, 0.f);
      float inter = w * h;
      float iou = inter / (areaA + areaB - inter + 1e-9f);
      if (iou > NMS_TH) bits |= (1ull << jj);
    }
  }
  mask[(size_t)i * 32 + bj] = bits;
}

// =====================================================================
// Sequential NMS scan (wave-synchronous, 32 lanes own 32 u64 words)
// + final compaction to d_out (boxes[1000][4] then scores[1000])
// =====================================================================
__global__ __launch_bounds__(1024) void nms_out_kernel(
    const float* __restrict__ boxes_s, const float* __restrict__ sc_s,
    const unsigned long long* __restrict__ mask, float* __restrict__ out) {
  int t = threadIdx.x;
  for (int e = t; e < (OUT_K * 4 + OUT_K); e += 1024) out[e] = 0.f;
  __shared__ unsigned long long keepw[32];
  if (t < 64) {
    int lane = t;
    unsigned long long removed = 0ull;
    if (lane < 32) {
      for (int k = 0; k < 64; ++k) {
        int idx = lane * 64 + k;
        if (idx >= PRE_K || sc_s[idx] < 0.f) removed |= (1ull << k);
      }
    }
    unsigned long long nxt = (lane < 32) ? mask[lane] : 0ull;
    for (int i = 0; i < PRE_K; ++i) {
      unsigned long long cur = nxt;
      if (lane < 32 && (i + 1) < PRE_K)
        nxt = mask[(size_t)(i + 1) * 32 + lane];
      unsigned long long ow = __shfl(removed, i >> 6);
      bool alive = ((ow >> (i & 63)) & 1ull) == 0ull;
      if (alive && lane < 32) removed |= cur;
    }
    if (lane < 32) keepw[lane] = ~removed;
  }
  __syncthreads();
  __shared__ unsigned int wbase[32];
  if (t == 0) {
    unsigned int s = 0;
    for (int k = 0; k < 32; ++k) {
      wbase[k] = s;
      s += (unsigned)__popcll(keepw[k]);
    }
  }
  __syncthreads();
  for (int i = t; i < PRE_K; i += 1024) {
    unsigned long long w = keepw[i >> 6];
    if ((w >> (i & 63)) & 1ull) {
      unsigned int pos =
          wbase[i >> 6] +
          (unsigned)__popcll(w & ((1ull << (i & 63)) - 1ull));
      if (pos < OUT_K) {
        out[pos * 4 + 0] = boxes_s[i * 4 + 0];
        out[pos * 4 + 1] = boxes_s[i * 4 + 1];
        out[pos * 4 + 2] = boxes_s[i * 4 + 2];
        out[pos * 4 + 3] = boxes_s[i * 4 + 3];
        out[OUT_K * 4 + pos] = sc_s[i];
      }
    }
  }
}

// =====================================================================
extern "C" void kernel_launch(void* const* d_in, const int* in_sizes, int n_in,
                              void* d_out, int out_size, void* d_ws,
                              size_t ws_size, hipStream_t stream) {
  const float* feat = (const float*)d_in[1];
  const float* convw = (const float*)d_in[2];
  const float* convb = (const float*)d_in[3];
  const float* clsw = (const float*)d_in[4];
  const float* clsb = (const float*)d_in[5];
  const float* regw = (const float*)d_in[6];
  const float* regb = (const float*)d_in[7];

  char* ws = (char*)d_ws;
  float* x = (float*)(ws + OFF_X);
  float* prop = (float*)(ws + OFF_PROP);
  float* score = (float*)(ws + OFF_SCORE);
  unsigned int* hist = (unsigned int*)(ws + OFF_HIST);
  unsigned int* state = (unsigned int*)(ws + OFF_STATE);
  unsigned long long* cand = (unsigned long long*)(ws + OFF_CAND);
  float* boxes_s = (float*)(ws + OFF_BOXS);
  float* sc_s = (float*)(ws + OFF_SCS);
  unsigned long long* mask = (unsigned long long*)(ws + OFF_MASK);
  float* out = (float*)d_out;

  // zero hist(1024B) + state(64B) each call (ws is re-poisoned 0xAA)
  hipMemsetAsync(ws + OFF_HIST, 0, 1024 + 64, stream);

  conv3x3_relu<<<dim3(4, 200, 4), 256, 0, stream>>>(feat, convw, convb, x);
  heads_kernel<<<79, 256, 0, stream>>>(x, clsw, clsb, regw, regb, prop, score);
  for (int p = 0; p < 4; ++p) {
    hist_kernel<<<256, 256, 0, stream>>>(score, hist, state, p);
    scan_kernel<<<1, 256, 0, stream>>>(hist, state, p);
  }
  collect_kernel<<<256, 256, 0, stream>>>(score, state, cand);
  sort_gather<<<1, 1024, 0, stream>>>(cand, state, prop, score, boxes_s, sc_s);
  iou_kernel<<<dim3(32, 32), 64, 0, stream>>>(boxes_s, mask);
  nms_out_kernel<<<1, 1024, 0, stream>>>(boxes_s, sc_s, mask, out);
}

// Round 2
// 1741.933 us; speedup vs baseline: 1.0550x; 1.0550x over previous
//
#include <hip/hip_runtime.h>
#include <math.h>

// ---------------- constants ----------------
#define FH 200
#define FW 200
#define HW 40000            // FH*FW
#define NUM_A 9
#define NANCH 360000        // HW*NUM_A
#define PRE_K 2000
#define OUT_K 1000
#define IMG_SZ 1600.0f
#define MIN_SZ 16.0f
#define NMS_TH 0.7f
#define BBOX_CLIP_F 4.135166556742356f   // log(1000/16)

// ---------------- workspace layout (bytes) ----------------
#define OFF_LOGIT  ((size_t)0)           // 40000*45*4 = 7,200,000
#define OFF_HIST   ((size_t)7200000)     // 256 u32   = 1,024
#define OFF_STATE  ((size_t)7201024)     // 16 u32    = 64
#define OFF_PROP   ((size_t)7201088)     // 360000*4f = 5,760,000 (16B aligned)
#define OFF_SCORE  ((size_t)12961088)    // 360000 f  = 1,440,000
#define OFF_CAND   ((size_t)14401088)    // 4096 u64  = 32,768
#define OFF_BOXS   ((size_t)14433856)    // 2000*4 f  = 32,000 (16B aligned)
#define OFF_SCS    ((size_t)14465856)    // 2000 f    = 8,000
#define OFF_MASK   ((size_t)14473856)    // 2000*32 u64 = 512,000

// =====================================================================
// Kernel 1: 3x3 conv + bias + ReLU, fused with 1x1 head partial dots.
// Tile: 128 co x 40 px (5 px-segs x 200 rows x 2 co-tiles = 2000 blocks).
// Threads: 256 = 8 tx (5 px each) x 32 ty (4 co each).
// Head partials (over this block's 128 ci) atomicAdd'ed into logits[px][45];
// exactly 2 addends per slot (co-tiles) -> commutative -> deterministic.
// =====================================================================
__global__ __launch_bounds__(256, 3) void conv_fused(
    const float* __restrict__ feat, const float* __restrict__ w,
    const float* __restrict__ bias, const float* __restrict__ cls_w,
    const float* __restrict__ reg_w, float* __restrict__ logits) {
  __shared__ float wlds[128 * 96];   // [co][ci*12 + tap]  (taps 0..8, pad 12)
  __shared__ float flds[8 * 3 * 44]; // [ci][row][44] cols 0..41 = px0-1..px0+40
  const int t = threadIdx.x;
  const int tx = t & 7;    // px group (5 px)
  const int ty = t >> 3;   // co group (4 co)
  const int px0 = blockIdx.x * 40;
  const int h = blockIdx.y;
  const int co0 = blockIdx.z * 128;

  float acc[4][5];
#pragma unroll
  for (int cc = 0; cc < 4; ++cc)
#pragma unroll
    for (int p = 0; p < 5; ++p) acc[cc][p] = 0.f;

  // ---- staging address precompute (all loop-invariant except +stride) ----
  // weights: thread stages half of one co's 8ci x 9tap = 36 floats
  const int co_l = t >> 1;
  const int half = t & 1;
  const float* wg = w + (size_t)(co0 + co_l) * 2304 + half * 36;
  float* wdst = &wlds[co_l * 96 + half * 48];
  // feat: 1008 floats = 8ci x 3row x 42col; threads t<252 stage 4 each
  const bool fw = (t < 252);
  const float* fg[4];
  float* fl[4];
  bool fval[4];
#pragma unroll
  for (int j = 0; j < 4; ++j) {
    int e = j * 252 + (t < 252 ? t : 0);
    int ci = e / 126;
    int rm = e - ci * 126;
    int r = rm / 42;
    int c = rm - r * 42;
    int hh = h - 1 + r;
    int ww = px0 - 1 + c;
    bool v = fw && ((unsigned)hh < (unsigned)FH) && ((unsigned)ww < (unsigned)FW);
    fval[j] = v;
    fg[j] = v ? (feat + (size_t)ci * HW + hh * FW + ww) : feat;
    fl[j] = &flds[(ci * 3 + r) * 44 + c];
  }

  for (int ci0 = 0; ci0 < 256; ci0 += 8) {
    __syncthreads();
    // stage weights: 9 float4 loads, repack to tap-padded layout
    float4 wq[9];
#pragma unroll
    for (int q = 0; q < 9; ++q) wq[q] = *(const float4*)(wg + q * 4);
    wg += 72;
#pragma unroll
    for (int q = 0; q < 9; ++q) {
      float v[4] = {wq[q].x, wq[q].y, wq[q].z, wq[q].w};
#pragma unroll
      for (int m = 0; m < 4; ++m) {
        int j = q * 4 + m;                 // 0..35, compile-time
        wdst[(j / 9) * 12 + (j % 9)] = v[m];
      }
    }
    // stage feat: 4 predicated loads
#pragma unroll
    for (int j = 0; j < 4; ++j) {
      float v = fval[j] ? *fg[j] : 0.f;
      fg[j] += 8 * HW;
      if (fw) *fl[j] = v;
    }
    __syncthreads();
    // compute: 8 ci x (4co x 9tap x 5px) FMA
#pragma unroll
    for (int ci = 0; ci < 8; ++ci) {
      float f[3][7];
#pragma unroll
      for (int r = 0; r < 3; ++r)
#pragma unroll
        for (int p = 0; p < 7; ++p)
          f[r][p] = flds[(ci * 3 + r) * 44 + tx * 5 + p];
#pragma unroll
      for (int cc = 0; cc < 4; ++cc) {
        const float* wp = &wlds[(ty * 4 + cc) * 96 + ci * 12];
        float wv[9];
#pragma unroll
        for (int tap = 0; tap < 9; ++tap) wv[tap] = wp[tap];
#pragma unroll
        for (int kh = 0; kh < 3; ++kh)
#pragma unroll
          for (int kw = 0; kw < 3; ++kw)
#pragma unroll
            for (int p = 0; p < 5; ++p)
              acc[cc][p] = fmaf(wv[kh * 3 + kw], f[kh][p + kw], acc[cc][p]);
      }
    }
  }

  // ---- epilogue: bias+relu, x-tile -> LDS, head partial dots ----
  float bv[4];
#pragma unroll
  for (int cc = 0; cc < 4; ++cc) bv[cc] = bias[co0 + ty * 4 + cc];
  __syncthreads();  // all waves done reading wlds/flds
  float* xl = wlds;               // [40 px][132] (co 0..127)
  float* hwt = wlds + 40 * 132;   // [45 k][132]  total 11220 < 12288 floats
#pragma unroll
  for (int p = 0; p < 5; ++p) {
    float4 v;
    v.x = fmaxf(acc[0][p] + bv[0], 0.f);
    v.y = fmaxf(acc[1][p] + bv[1], 0.f);
    v.z = fmaxf(acc[2][p] + bv[2], 0.f);
    v.w = fmaxf(acc[3][p] + bv[3], 0.f);
    *(float4*)&xl[(tx * 5 + p) * 132 + ty * 4] = v;
  }
  for (int e = t; e < 45 * 128; e += 256) {
    int k = e >> 7;
    int c = e & 127;
    float v = (k < 9) ? cls_w[k * 256 + co0 + c]
                      : reg_w[(k - 9) * 256 + co0 + c];
    hwt[k * 132 + c] = v;
  }
  __syncthreads();
  const int gpx0 = h * 200 + px0;
  for (int s = t; s < 1800; s += 256) {
    int px = s / 45;
    int k = s - px * 45;
    const float4* xp = (const float4*)&xl[px * 132];
    const float4* wp = (const float4*)&hwt[k * 132];
    float a = 0.f;
#pragma unroll
    for (int q = 0; q < 32; ++q) {
      float4 xv = xp[q], wv = wp[q];
      a = fmaf(xv.x, wv.x, a);
      a = fmaf(xv.y, wv.y, a);
      a = fmaf(xv.z, wv.z, a);
      a = fmaf(xv.w, wv.w, a);
    }
    atomicAdd(&logits[(size_t)(gpx0 + px) * 45 + k], a);
  }
}

// =====================================================================
// Kernel 2: finalize — bias + anchors + deltas + sigmoid from logits
// =====================================================================
__global__ __launch_bounds__(256) void finalize_kernel(
    const float* __restrict__ logits, const float* __restrict__ cls_b,
    const float* __restrict__ reg_b, float* __restrict__ prop,
    float* __restrict__ score) {
  int px = blockIdx.x * 256 + threadIdx.x;
  if (px >= HW) return;
  float A[45];
  const float* lp = logits + (size_t)px * 45;
#pragma unroll
  for (int i = 0; i < 45; ++i) A[i] = lp[i];
  const float scv[3] = {128.f, 256.f, 512.f};
  const float arv[3] = {0.5f, 1.f, 2.f};
  float sx = (float)(px % FW) * 8.0f;
  float sy = (float)(px / FW) * 8.0f;
#pragma unroll
  for (int a = 0; a < NUM_A; ++a) {
    int ai = a / 3, si = a % 3;
    float hr = sqrtf(arv[ai]);
    float wr = 1.0f / hr;
    float rw = nearbyintf(wr * scv[si] * 0.5f);
    float rh = nearbyintf(hr * scv[si] * 0.5f);
    float ax0 = sx - rw, ay0 = sy - rh, ax1 = sx + rw, ay1 = sy + rh;
    float aw = ax1 - ax0, ah = ay1 - ay0;
    float cx = ax0 + 0.5f * aw, cy = ay0 + 0.5f * ah;
    float dx = A[9 + a * 4 + 0] + reg_b[a * 4 + 0];
    float dy = A[9 + a * 4 + 1] + reg_b[a * 4 + 1];
    float dw = fminf(A[9 + a * 4 + 2] + reg_b[a * 4 + 2], BBOX_CLIP_F);
    float dh = fminf(A[9 + a * 4 + 3] + reg_b[a * 4 + 3], BBOX_CLIP_F);
    float pcx = dx * aw + cx;
    float pcy = dy * ah + cy;
    float pw = expf(dw) * aw;
    float ph = expf(dh) * ah;
    size_t base = (size_t)(px * NUM_A + a) * 4;
    prop[base + 0] = pcx - 0.5f * pw;
    prop[base + 1] = pcy - 0.5f * ph;
    prop[base + 2] = pcx + 0.5f * pw;
    prop[base + 3] = pcy + 0.5f * ph;
    float lg = A[a] + cls_b[a];
    score[px * NUM_A + a] = 1.0f / (1.0f + expf(-lg));
  }
}

// =====================================================================
// Radix select (4 passes of 8 bits) for exact top-2000 threshold
// =====================================================================
__global__ __launch_bounds__(256) void hist_kernel(
    const float* __restrict__ score, unsigned int* __restrict__ hist,
    const unsigned int* __restrict__ state, int pass) {
  __shared__ unsigned int h[256];
  int t = threadIdx.x;
  h[t] = 0;
  __syncthreads();
  unsigned int prefix = (pass == 0) ? 0u : state[0];
  int shift = 24 - 8 * pass;
  for (int i = blockIdx.x * 256 + t; i < NANCH; i += gridDim.x * 256) {
    unsigned int key = __float_as_uint(score[i]);
    bool m = (pass == 0) || ((key >> (32 - 8 * pass)) == prefix);
    if (m) atomicAdd(&h[(key >> shift) & 255u], 1u);
  }
  __syncthreads();
  if (h[t]) atomicAdd(&hist[t], h[t]);
}

__global__ __launch_bounds__(256) void scan_kernel(
    unsigned int* __restrict__ hist, unsigned int* __restrict__ state, int pass) {
  __shared__ unsigned int s0[256], s1[256];
  int t = threadIdx.x;
  unsigned int hv = hist[t];
  hist[t] = 0u;  // pre-zero for next pass
  s0[t] = hv;
  __syncthreads();
  unsigned int* A = s0;
  unsigned int* B = s1;
  for (int off = 1; off < 256; off <<= 1) {
    B[t] = A[t] + ((t + off < 256) ? A[t + off] : 0u);
    __syncthreads();
    unsigned int* tmp = A; A = B; B = tmp;
  }
  unsigned int prefix = (pass == 0) ? 0u : state[0];
  unsigned int rem = (pass == 0) ? (unsigned)PRE_K : state[1];
  unsigned int suf = A[t];
  unsigned int sufn = (t < 255) ? A[t + 1] : 0u;
  if (suf >= rem && sufn < rem) {
    state[0] = (prefix << 8) | (unsigned int)t;
    state[1] = rem - sufn;
  }
}

__global__ __launch_bounds__(256) void collect_kernel(
    const float* __restrict__ score, unsigned int* __restrict__ state,
    unsigned long long* __restrict__ cand) {
  unsigned int T = state[0];
  for (int i = blockIdx.x * 256 + threadIdx.x; i < NANCH; i += gridDim.x * 256) {
    unsigned int key = __float_as_uint(score[i]);
    if (key >= T) {
      unsigned int pos = atomicAdd(&state[4], 1u);
      if (pos < 4096u)
        cand[pos] = ((unsigned long long)key << 32) |
                    (unsigned long long)(~(unsigned int)i);
    }
  }
}

// =====================================================================
// Bitonic sort + gather + clip + valid + stable partition
// =====================================================================
__global__ __launch_bounds__(1024) void sort_gather(
    const unsigned long long* __restrict__ cand,
    const unsigned int* __restrict__ state, const float* __restrict__ prop,
    const float* __restrict__ score, float* __restrict__ boxes_s,
    float* __restrict__ sc_s) {
  __shared__ unsigned long long sk[4096];
  int t = threadIdx.x;
  unsigned int cnt = state[4];
  if (cnt > 4096u) cnt = 4096u;
  for (int e = t; e < 4096; e += 1024) sk[e] = (e < (int)cnt) ? cand[e] : 0ull;
  __syncthreads();
  for (int k = 2; k <= 4096; k <<= 1) {
    for (int j = k >> 1; j > 0; j >>= 1) {
      for (int i = t; i < 4096; i += 1024) {
        int l = i ^ j;
        if (l > i) {
          unsigned long long a = sk[i], bb = sk[l];
          bool up = ((i & k) == 0);
          bool sw = up ? (a < bb) : (a > bb);
          if (sw) { sk[i] = bb; sk[l] = a; }
        }
      }
      __syncthreads();
    }
  }
  float bx[2][4];
  float sc2[2] = {-1.f, -1.f};
  bool valid2[2] = {false, false};
#pragma unroll
  for (int s = 0; s < 2; ++s) {
    int i = t + s * 1024;
    bx[s][0] = bx[s][1] = bx[s][2] = bx[s][3] = 0.f;
    if (i < PRE_K) {
      unsigned long long v = sk[i];
      unsigned int idx = ~(unsigned int)(v & 0xFFFFFFFFull);
      float4 p = *(const float4*)(prop + (size_t)idx * 4);
      float x0 = fminf(fmaxf(p.x, 0.f), IMG_SZ);
      float y0 = fminf(fmaxf(p.y, 0.f), IMG_SZ);
      float x1 = fminf(fmaxf(p.z, 0.f), IMG_SZ);
      float y1 = fminf(fmaxf(p.w, 0.f), IMG_SZ);
      bool valid = (x1 - x0 >= MIN_SZ) && (y1 - y0 >= MIN_SZ);
      bx[s][0] = x0; bx[s][1] = y0; bx[s][2] = x1; bx[s][3] = y1;
      valid2[s] = valid;
      sc2[s] = valid ? score[idx] : -1.0f;
    }
  }
  __syncthreads();
  int* A = (int*)sk;
  int* B = A + 2048;
#pragma unroll
  for (int s = 0; s < 2; ++s) {
    int i = t + s * 1024;
    A[i] = (i < PRE_K && valid2[s]) ? 1 : 0;
  }
  __syncthreads();
  for (int off = 1; off < 2048; off <<= 1) {
#pragma unroll
    for (int s = 0; s < 2; ++s) {
      int i = t + s * 1024;
      B[i] = A[i] + ((i >= off) ? A[i - off] : 0);
    }
    __syncthreads();
    int* tmp = A; A = B; B = tmp;
  }
  int total = A[2047];
#pragma unroll
  for (int s = 0; s < 2; ++s) {
    int i = t + s * 1024;
    if (i < PRE_K) {
      int inc = A[i];
      int pos = valid2[s] ? (inc - 1) : (total + (i - inc));
      boxes_s[pos * 4 + 0] = bx[s][0];
      boxes_s[pos * 4 + 1] = bx[s][1];
      boxes_s[pos * 4 + 2] = bx[s][2];
      boxes_s[pos * 4 + 3] = bx[s][3];
      sc_s[pos] = sc2[s];
    }
  }
}

// =====================================================================
// IoU suppression bitmask
// =====================================================================
__global__ __launch_bounds__(64) void iou_kernel(
    const float* __restrict__ boxes_s, unsigned long long* __restrict__ mask) {
  int bi = blockIdx.y, bj = blockIdx.x;
  int t = threadIdx.x;
  __shared__ float4 cb[64];
  int jc = bj * 64 + t;
  float4 z; z.x = z.y = z.z = z.w = 0.f;
  cb[t] = (jc < PRE_K) ? *(const float4*)(boxes_s + (size_t)jc * 4) : z;
  __syncthreads();
  int i = bi * 64 + t;
  if (i >= PRE_K) return;
  float4 a = *(const float4*)(boxes_s + (size_t)i * 4);
  float areaA = (a.z - a.x) * (a.w - a.y);
  unsigned long long bits = 0ull;
  for (int jj = 0; jj < 64; ++jj) {
    int j = bj * 64 + jj;
    if (j < PRE_K && j > i) {
      float4 b = cb[jj];
      float areaB = (b.z - b.x) * (b.w - b.y);
      float ltx = fmaxf(a.x, b.x), lty = fmaxf(a.y, b.y);
      float rbx = fminf(a.z, b.z), rby = fminf(a.w, b.w);
      float w = fmaxf(rbx - ltx, 0.f), h = fmaxf(rby - lty, 0.f);
      float inter = w * h;
      float iou = inter / (areaA + areaB - inter + 1e-9f);
      if (iou > NMS_TH) bits |= (1ull << jj);
    }
  }
  mask[(size_t)i * 32 + bj] = bits;
}

// =====================================================================
// Sequential NMS scan + final compaction to d_out
// =====================================================================
__global__ __launch_bounds__(1024) void nms_out_kernel(
    const float* __restrict__ boxes_s, const float* __restrict__ sc_s,
    const unsigned long long* __restrict__ mask, float* __restrict__ out) {
  int t = threadIdx.x;
  for (int e = t; e < (OUT_K * 4 + OUT_K); e += 1024) out[e] = 0.f;
  __shared__ unsigned long long keepw[32];
  if (t < 64) {
    int lane = t;
    unsigned long long removed = 0ull;
    if (lane < 32) {
      for (int k = 0; k < 64; ++k) {
        int idx = lane * 64 + k;
        if (idx >= PRE_K || sc_s[idx] < 0.f) removed |= (1ull << k);
      }
    }
    unsigned long long nxt = (lane < 32) ? mask[lane] : 0ull;
    for (int i = 0; i < PRE_K; ++i) {
      unsigned long long cur = nxt;
      if (lane < 32 && (i + 1) < PRE_K)
        nxt = mask[(size_t)(i + 1) * 32 + lane];
      unsigned long long ow = __shfl(removed, i >> 6);
      bool alive = ((ow >> (i & 63)) & 1ull) == 0ull;
      if (alive && lane < 32) removed |= cur;
    }
    if (lane < 32) keepw[lane] = ~removed;
  }
  __syncthreads();
  __shared__ unsigned int wbase[32];
  if (t == 0) {
    unsigned int s = 0;
    for (int k = 0; k < 32; ++k) {
      wbase[k] = s;
      s += (unsigned)__popcll(keepw[k]);
    }
  }
  __syncthreads();
  for (int i = t; i < PRE_K; i += 1024) {
    unsigned long long w = keepw[i >> 6];
    if ((w >> (i & 63)) & 1ull) {
      unsigned int pos =
          wbase[i >> 6] +
          (unsigned)__popcll(w & ((1ull << (i & 63)) - 1ull));
      if (pos < OUT_K) {
        out[pos * 4 + 0] = boxes_s[i * 4 + 0];
        out[pos * 4 + 1] = boxes_s[i * 4 + 1];
        out[pos * 4 + 2] = boxes_s[i * 4 + 2];
        out[pos * 4 + 3] = boxes_s[i * 4 + 3];
        out[OUT_K * 4 + pos] = sc_s[i];
      }
    }
  }
}

// =====================================================================
extern "C" void kernel_launch(void* const* d_in, const int* in_sizes, int n_in,
                              void* d_out, int out_size, void* d_ws,
                              size_t ws_size, hipStream_t stream) {
  const float* feat = (const float*)d_in[1];
  const float* convw = (const float*)d_in[2];
  const float* convb = (const float*)d_in[3];
  const float* clsw = (const float*)d_in[4];
  const float* clsb = (const float*)d_in[5];
  const float* regw = (const float*)d_in[6];
  const float* regb = (const float*)d_in[7];

  char* ws = (char*)d_ws;
  float* logits = (float*)(ws + OFF_LOGIT);
  unsigned int* hist = (unsigned int*)(ws + OFF_HIST);
  unsigned int* state = (unsigned int*)(ws + OFF_STATE);
  float* prop = (float*)(ws + OFF_PROP);
  float* score = (float*)(ws + OFF_SCORE);
  unsigned long long* cand = (unsigned long long*)(ws + OFF_CAND);
  float* boxes_s = (float*)(ws + OFF_BOXS);
  float* sc_s = (float*)(ws + OFF_SCS);
  unsigned long long* mask = (unsigned long long*)(ws + OFF_MASK);
  float* out = (float*)d_out;

  // zero logits + hist + state in one memset
  hipMemsetAsync(ws, 0, OFF_STATE + 64, stream);

  conv_fused<<<dim3(5, 200, 2), 256, 0, stream>>>(feat, convw, convb, clsw,
                                                  regw, logits);
  finalize_kernel<<<157, 256, 0, stream>>>(logits, clsb, regb, prop, score);
  for (int p = 0; p < 4; ++p) {
    hist_kernel<<<256, 256, 0, stream>>>(score, hist, state, p);
    scan_kernel<<<1, 256, 0, stream>>>(hist, state, p);
  }
  collect_kernel<<<256, 256, 0, stream>>>(score, state, cand);
  sort_gather<<<1, 1024, 0, stream>>>(cand, state, prop, score, boxes_s, sc_s);
  iou_kernel<<<dim3(32, 32), 64, 0, stream>>>(boxes_s, mask);
  nms_out_kernel<<<1, 1024, 0, stream>>>(boxes_s, sc_s, mask, out);
}

// Round 4
// 1090.847 us; speedup vs baseline: 1.6848x; 1.5969x over previous
//
#include <hip/hip_runtime.h>
#include <math.h>

// ---------------- constants ----------------
#define FH 200
#define FW 200
#define HW 40000            // FH*FW
#define NUM_A 9
#define NANCH 360000        // HW*NUM_A
#define PRE_K 2000
#define OUT_K 1000
#define IMG_SZ 1600.0f
#define MIN_SZ 16.0f
#define NMS_TH 0.7f
#define BBOX_CLIP_F 4.135166556742356f   // log(1000/16)

// ---------------- workspace layout (bytes), total ~18.6 MB ----------------
#define OFF_LOGIT  ((size_t)0)           // 40000*45*4 = 7,200,000
#define OFF_HIST   ((size_t)7200000)     // 256 u32 = 1024
#define OFF_STATE  ((size_t)7201024)     // 16 u32 = 64
#define OFF_CAND   ((size_t)7201088)     // 4096 u64 = 32,768
#define OFF_BOXS   ((size_t)7233856)     // 2000*4 f = 32,000
#define OFF_SCS    ((size_t)7265856)     // 2000 f = 8,000
#define OFF_MASK   ((size_t)7273856)     // 2000*32 u64 = 512,000
#define OFF_AWH    ((size_t)7785856)     // 16*9*8*64*16B = 1,179,648
#define OFF_AWM    ((size_t)8965504)
#define OFF_AWL    ((size_t)10145152)
#define OFF_HWH    ((size_t)11324800)    // 3*8*64*16B = 24,576
#define OFF_HWM    ((size_t)11349376)
#define OFF_HWL    ((size_t)11373952)
#define OFF_PROP   ((size_t)11398528)    // 360000*4 f = 5,760,000
#define OFF_SCORE  ((size_t)17158528)    // 360000 f = 1,440,000 -> 18,598,528

typedef __attribute__((ext_vector_type(8))) short short8;
typedef __attribute__((ext_vector_type(4))) float floatx4;
#define MFMA16(a, b, c) __builtin_amdgcn_mfma_f32_16x16x32_bf16(a, b, c, 0, 0, 0)

__device__ __forceinline__ unsigned short rne_bf16(float v) {
  unsigned int bb = __float_as_uint(v);
  return (unsigned short)((bb + 0x7FFFu + ((bb >> 16) & 1u)) >> 16);
}

// 3-way split: v = h + m + l + eps, |eps| <~ 2^-25 |v|
__device__ __forceinline__ void split3(float v, unsigned short& h,
                                       unsigned short& m, unsigned short& l) {
  h = rne_bf16(v);
  float r1 = v - __uint_as_float(((unsigned int)h) << 16);
  m = rne_bf16(r1);
  float r2 = r1 - __uint_as_float(((unsigned int)m) << 16);
  l = rne_bf16(r2);
}

// =====================================================================
// Prepass: swizzle conv weights + head weights into MFMA A-fragment
// order (lane L of tile ctg holds W[ctg*16+(L&15)][k=cib*32+(L>>4)*8+j]),
// 3-way bf16 split (hi/mid/lo planes).
// AW: 16 co-tiles x 9 taps x 8 ci-blocks x 64 lanes x 16B.
// HwF: 3 head-tiles (48 rows >= 45) x 8 co-blocks x 64 lanes x 16B.
// =====================================================================
__global__ __launch_bounds__(256) void prep_weights(
    const float* __restrict__ w, const float* __restrict__ cls_w,
    const float* __restrict__ reg_w, uint4* __restrict__ AW_h,
    uint4* __restrict__ AW_m, uint4* __restrict__ AW_l,
    uint4* __restrict__ HwF_h, uint4* __restrict__ HwF_m,
    uint4* __restrict__ HwF_l) {
  int gid = blockIdx.x * 256 + threadIdx.x;
  unsigned short h[8], m[8], l[8];
  if (gid < 73728) {
    int L = gid & 63;
    int idx = gid >> 6;            // (ctg*9+tap)*8 + cib
    int cib = idx & 7;
    int tmp = idx >> 3;
    int tap = tmp % 9;
    int ctg = tmp / 9;
    int co = ctg * 16 + (L & 15);
    int ci0 = cib * 32 + (L >> 4) * 8;
#pragma unroll
    for (int j = 0; j < 8; ++j)
      split3(w[(size_t)co * 2304 + (ci0 + j) * 9 + tap], h[j], m[j], l[j]);
    uint4 vh, vm, vl;
    vh.x = h[0] | (h[1] << 16); vh.y = h[2] | (h[3] << 16);
    vh.z = h[4] | (h[5] << 16); vh.w = h[6] | (h[7] << 16);
    vm.x = m[0] | (m[1] << 16); vm.y = m[2] | (m[3] << 16);
    vm.z = m[4] | (m[5] << 16); vm.w = m[6] | (m[7] << 16);
    vl.x = l[0] | (l[1] << 16); vl.y = l[2] | (l[3] << 16);
    vl.z = l[4] | (l[5] << 16); vl.w = l[6] | (l[7] << 16);
    AW_h[gid] = vh; AW_m[gid] = vm; AW_l[gid] = vl;
  } else if (gid < 73728 + 1536) {
    int g2 = gid - 73728;
    int L = g2 & 63;
    int idx = g2 >> 6;             // mt*8 + kb
    int kb = idx & 7;
    int mt = idx >> 3;
    int mm = mt * 16 + (L & 15);
    int co0 = kb * 32 + (L >> 4) * 8;
#pragma unroll
    for (int j = 0; j < 8; ++j) {
      float v = 0.f;
      if (mm < 9) v = cls_w[mm * 256 + co0 + j];
      else if (mm < 45) v = reg_w[(mm - 9) * 256 + co0 + j];
      split3(v, h[j], m[j], l[j]);
    }
    uint4 vh, vm, vl;
    vh.x = h[0] | (h[1] << 16); vh.y = h[2] | (h[3] << 16);
    vh.z = h[4] | (h[5] << 16); vh.w = h[6] | (h[7] << 16);
    vm.x = m[0] | (m[1] << 16); vm.y = m[2] | (m[3] << 16);
    vm.z = m[4] | (m[5] << 16); vm.w = m[6] | (m[7] << 16);
    vl.x = l[0] | (l[1] << 16); vl.y = l[2] | (l[3] << 16);
    vl.z = l[4] | (l[5] << 16); vl.w = l[6] | (l[7] << 16);
    HwF_h[g2] = vh; HwF_m[g2] = vm; HwF_l[g2] = vl;
  }
}

// =====================================================================
// Main conv+heads MFMA kernel (3-way split, 6 products ~= fp32 accuracy).
// Block tile: 128 co (cb half) x 128 px (8 rows x 16 cols).
// Grid: (13 col-segs x 25 row-groups x 2 co-halves).  4 waves; wave wv owns
// co-tiles {wv*2, wv*2+1} across all 8 px-row tiles.
// Staging: fp32 feat loaded directly (no transpose prepass), split3 into
// 3 LDS planes [row10][col18][ci-pad40] u16.
// Epilogue: bias+ReLU, x -> LDS 3-plane bf16, head GEMM, atomicAdd into
// logits[px][45] (exactly 2 addends per slot -> deterministic).
// =====================================================================
__global__ __launch_bounds__(256) void conv_mfma(
    const float* __restrict__ feat, const uint4* __restrict__ AW_h,
    const uint4* __restrict__ AW_m, const uint4* __restrict__ AW_l,
    const uint4* __restrict__ HwF_h, const uint4* __restrict__ HwF_m,
    const uint4* __restrict__ HwF_l, const float* __restrict__ bias,
    float* __restrict__ logits) {
  __shared__ alignas(16) unsigned short smem[26112];  // 52,224 B
  const int t = threadIdx.x;
  const int L = t & 63, wv = t >> 6;
  const int q = L >> 4, nl = L & 15;
  const int w0 = blockIdx.x * 16;
  const int h0 = blockIdx.y * 8;
  const int cb = blockIdx.z;

  floatx4 acc[2][8];
#pragma unroll
  for (int ct = 0; ct < 2; ++ct)
#pragma unroll
    for (int r = 0; r < 8; ++r) acc[ct][r] = (floatx4)0.f;

  unsigned short* flh = smem;          // [10 rows][18 cols][40 ci-pad] u16
  unsigned short* flm = smem + 7200;
  unsigned short* fll = smem + 14400;

  for (int cib = 0; cib < 8; ++cib) {
    __syncthreads();
    // stage 32ci x 10row x 18col fp32 -> split3 -> 3 LDS planes
#pragma unroll
    for (int j = 0; j < 23; ++j) {
      int e = j * 256 + t;
      if (e < 5760) {
        int ci = e / 180;
        int rem = e - ci * 180;
        int rr = rem / 18;
        int cc = rem - rr * 18;
        int gr = h0 - 1 + rr, gc = w0 - 1 + cc;
        float v = 0.f;
        if ((unsigned)gr < (unsigned)FH && (unsigned)gc < (unsigned)FW)
          v = feat[(size_t)(cib * 32 + ci) * HW + gr * FW + gc];
        unsigned short hh, mm, ll;
        split3(v, hh, mm, ll);
        int off = rr * 720 + cc * 40 + ci;
        flh[off] = hh; flm[off] = mm; fll[off] = ll;
      }
    }
    __syncthreads();
    const int ctg0 = cb * 8 + wv * 2;
    for (int kh = 0; kh < 3; ++kh) {
      for (int kw = 0; kw < 3; ++kw) {
        const int tap = kh * 3 + kw;
        const int abase = ((ctg0 * 9 + tap) * 8 + cib) * 64 + L;
        const int abase1 = abase + 9 * 8 * 64;
        short8 ah0 = ((const short8*)AW_h)[abase];
        short8 am0 = ((const short8*)AW_m)[abase];
        short8 al0 = ((const short8*)AW_l)[abase];
        short8 ah1 = ((const short8*)AW_h)[abase1];
        short8 am1 = ((const short8*)AW_m)[abase1];
        short8 al1 = ((const short8*)AW_l)[abase1];
        const int cbase = (nl + kw) * 40 + q * 8;
#pragma unroll
        for (int r = 0; r < 8; ++r) {
          const int off = (r + kh) * 720 + cbase;
          short8 bh = *(const short8*)(flh + off);
          short8 bm = *(const short8*)(flm + off);
          short8 bl = *(const short8*)(fll + off);
          acc[0][r] = MFMA16(ah0, bh, acc[0][r]);
          acc[0][r] = MFMA16(ah0, bm, acc[0][r]);
          acc[0][r] = MFMA16(am0, bh, acc[0][r]);
          acc[0][r] = MFMA16(ah0, bl, acc[0][r]);
          acc[0][r] = MFMA16(am0, bm, acc[0][r]);
          acc[0][r] = MFMA16(al0, bh, acc[0][r]);
          acc[1][r] = MFMA16(ah1, bh, acc[1][r]);
          acc[1][r] = MFMA16(ah1, bm, acc[1][r]);
          acc[1][r] = MFMA16(am1, bh, acc[1][r]);
          acc[1][r] = MFMA16(ah1, bl, acc[1][r]);
          acc[1][r] = MFMA16(am1, bm, acc[1][r]);
          acc[1][r] = MFMA16(al1, bh, acc[1][r]);
        }
      }
    }
  }

  // ---- epilogue ----
  float bv[2][4];
#pragma unroll
  for (int ct = 0; ct < 2; ++ct)
#pragma unroll
    for (int i = 0; i < 4; ++i)
      bv[ct][i] = bias[cb * 128 + (wv * 2 + ct) * 16 + q * 4 + i];

  unsigned short* xlh = smem;           // [64 px][136 co-pad] u16
  unsigned short* xlm = smem + 8704;
  unsigned short* xll = smem + 17408;

  for (int hp = 0; hp < 2; ++hp) {
    __syncthreads();  // prior smem reads complete
#pragma unroll
    for (int ct = 0; ct < 2; ++ct) {
#pragma unroll
      for (int rr = 0; rr < 4; ++rr) {
        int r = hp * 4 + rr;
        unsigned short xh[4], xm[4], xl_[4];
#pragma unroll
        for (int i = 0; i < 4; ++i) {
          float xv = fmaxf(acc[ct][r][i] + bv[ct][i], 0.f);
          split3(xv, xh[i], xm[i], xl_[i]);
        }
        int px_l = rr * 16 + nl;
        int co_l = (wv * 2 + ct) * 16 + q * 4;
        uint2 ph, pm, pl;
        ph.x = xh[0] | (xh[1] << 16); ph.y = xh[2] | (xh[3] << 16);
        pm.x = xm[0] | (xm[1] << 16); pm.y = xm[2] | (xm[3] << 16);
        pl.x = xl_[0] | (xl_[1] << 16); pl.y = xl_[2] | (xl_[3] << 16);
        *(uint2*)(xlh + px_l * 136 + co_l) = ph;
        *(uint2*)(xlm + px_l * 136 + co_l) = pm;
        *(uint2*)(xll + px_l * 136 + co_l) = pl;
      }
    }
    __syncthreads();
    // heads: wave wv -> px row (h0 + hp*4 + wv), cols w0..w0+15
    floatx4 ha[3];
#pragma unroll
    for (int mt = 0; mt < 3; ++mt) ha[mt] = (floatx4)0.f;
    for (int ks = 0; ks < 4; ++ks) {
      const int off = (wv * 16 + nl) * 136 + ks * 32 + q * 8;
      short8 bh = *(const short8*)(xlh + off);
      short8 bm = *(const short8*)(xlm + off);
      short8 bl = *(const short8*)(xll + off);
#pragma unroll
      for (int mt = 0; mt < 3; ++mt) {
        const int hb = (mt * 8 + cb * 4 + ks) * 64 + L;
        short8 hh = ((const short8*)HwF_h)[hb];
        short8 hm = ((const short8*)HwF_m)[hb];
        short8 hl = ((const short8*)HwF_l)[hb];
        ha[mt] = MFMA16(hh, bh, ha[mt]);
        ha[mt] = MFMA16(hh, bm, ha[mt]);
        ha[mt] = MFMA16(hm, bh, ha[mt]);
        ha[mt] = MFMA16(hh, bl, ha[mt]);
        ha[mt] = MFMA16(hm, bm, ha[mt]);
        ha[mt] = MFMA16(hl, bh, ha[mt]);
      }
    }
    int gr = h0 + hp * 4 + wv;
    int gc = w0 + nl;
    if (gc < FW) {
#pragma unroll
      for (int mt = 0; mt < 3; ++mt)
#pragma unroll
        for (int i = 0; i < 4; ++i) {
          int head = mt * 16 + q * 4 + i;
          if (head < 45)
            atomicAdd(&logits[(size_t)(gr * FW + gc) * 45 + head], ha[mt][i]);
        }
    }
  }
}

// =====================================================================
// finalize — bias + anchors + deltas + sigmoid from logits
// =====================================================================
__global__ __launch_bounds__(256) void finalize_kernel(
    const float* __restrict__ logits, const float* __restrict__ cls_b,
    const float* __restrict__ reg_b, float* __restrict__ prop,
    float* __restrict__ score) {
  int px = blockIdx.x * 256 + threadIdx.x;
  if (px >= HW) return;
  float A[45];
  const float* lp = logits + (size_t)px * 45;
#pragma unroll
  for (int i = 0; i < 45; ++i) A[i] = lp[i];
  const float scv[3] = {128.f, 256.f, 512.f};
  const float arv[3] = {0.5f, 1.f, 2.f};
  float sx = (float)(px % FW) * 8.0f;
  float sy = (float)(px / FW) * 8.0f;
#pragma unroll
  for (int a = 0; a < NUM_A; ++a) {
    int ai = a / 3, si = a % 3;
    float hr = sqrtf(arv[ai]);
    float wr = 1.0f / hr;
    float rw = nearbyintf(wr * scv[si] * 0.5f);
    float rh = nearbyintf(hr * scv[si] * 0.5f);
    float ax0 = sx - rw, ay0 = sy - rh, ax1 = sx + rw, ay1 = sy + rh;
    float aw = ax1 - ax0, ah = ay1 - ay0;
    float cx = ax0 + 0.5f * aw, cy = ay0 + 0.5f * ah;
    float dx = A[9 + a * 4 + 0] + reg_b[a * 4 + 0];
    float dy = A[9 + a * 4 + 1] + reg_b[a * 4 + 1];
    float dw = fminf(A[9 + a * 4 + 2] + reg_b[a * 4 + 2], BBOX_CLIP_F);
    float dh = fminf(A[9 + a * 4 + 3] + reg_b[a * 4 + 3], BBOX_CLIP_F);
    float pcx = dx * aw + cx;
    float pcy = dy * ah + cy;
    float pw = expf(dw) * aw;
    float ph = expf(dh) * ah;
    size_t base = (size_t)(px * NUM_A + a) * 4;
    prop[base + 0] = pcx - 0.5f * pw;
    prop[base + 1] = pcy - 0.5f * ph;
    prop[base + 2] = pcx + 0.5f * pw;
    prop[base + 3] = pcy + 0.5f * ph;
    float lg = A[a] + cls_b[a];
    score[px * NUM_A + a] = 1.0f / (1.0f + expf(-lg));
  }
}

// =====================================================================
// Radix select (4 passes of 8 bits) for exact top-2000 threshold
// =====================================================================
__global__ __launch_bounds__(256) void hist_kernel(
    const float* __restrict__ score, unsigned int* __restrict__ hist,
    const unsigned int* __restrict__ state, int pass) {
  __shared__ unsigned int h[256];
  int t = threadIdx.x;
  h[t] = 0;
  __syncthreads();
  unsigned int prefix = (pass == 0) ? 0u : state[0];
  int shift = 24 - 8 * pass;
  for (int i = blockIdx.x * 256 + t; i < NANCH; i += gridDim.x * 256) {
    unsigned int key = __float_as_uint(score[i]);
    bool m = (pass == 0) || ((key >> (32 - 8 * pass)) == prefix);
    if (m) atomicAdd(&h[(key >> shift) & 255u], 1u);
  }
  __syncthreads();
  if (h[t]) atomicAdd(&hist[t], h[t]);
}

__global__ __launch_bounds__(256) void scan_kernel(
    unsigned int* __restrict__ hist, unsigned int* __restrict__ state, int pass) {
  __shared__ unsigned int s0[256], s1[256];
  int t = threadIdx.x;
  unsigned int hv = hist[t];
  hist[t] = 0u;
  s0[t] = hv;
  __syncthreads();
  unsigned int* A = s0;
  unsigned int* B = s1;
  for (int off = 1; off < 256; off <<= 1) {
    B[t] = A[t] + ((t + off < 256) ? A[t + off] : 0u);
    __syncthreads();
    unsigned int* tmp = A; A = B; B = tmp;
  }
  unsigned int prefix = (pass == 0) ? 0u : state[0];
  unsigned int rem = (pass == 0) ? (unsigned)PRE_K : state[1];
  unsigned int suf = A[t];
  unsigned int sufn = (t < 255) ? A[t + 1] : 0u;
  if (suf >= rem && sufn < rem) {
    state[0] = (prefix << 8) | (unsigned int)t;
    state[1] = rem - sufn;
  }
}

__global__ __launch_bounds__(256) void collect_kernel(
    const float* __restrict__ score, unsigned int* __restrict__ state,
    unsigned long long* __restrict__ cand) {
  unsigned int T = state[0];
  for (int i = blockIdx.x * 256 + threadIdx.x; i < NANCH; i += gridDim.x * 256) {
    unsigned int key = __float_as_uint(score[i]);
    if (key >= T) {
      unsigned int pos = atomicAdd(&state[4], 1u);
      if (pos < 4096u)
        cand[pos] = ((unsigned long long)key << 32) |
                    (unsigned long long)(~(unsigned int)i);
    }
  }
}

// =====================================================================
// Bitonic sort + gather + clip + valid + stable partition
// =====================================================================
__global__ __launch_bounds__(1024) void sort_gather(
    const unsigned long long* __restrict__ cand,
    const unsigned int* __restrict__ state, const float* __restrict__ prop,
    const float* __restrict__ score, float* __restrict__ boxes_s,
    float* __restrict__ sc_s) {
  __shared__ unsigned long long sk[4096];
  int t = threadIdx.x;
  unsigned int cnt = state[4];
  if (cnt > 4096u) cnt = 4096u;
  for (int e = t; e < 4096; e += 1024) sk[e] = (e < (int)cnt) ? cand[e] : 0ull;
  __syncthreads();
  for (int k = 2; k <= 4096; k <<= 1) {
    for (int j = k >> 1; j > 0; j >>= 1) {
      for (int i = t; i < 4096; i += 1024) {
        int l = i ^ j;
        if (l > i) {
          unsigned long long a = sk[i], bb = sk[l];
          bool up = ((i & k) == 0);
          bool sw = up ? (a < bb) : (a > bb);
          if (sw) { sk[i] = bb; sk[l] = a; }
        }
      }
      __syncthreads();
    }
  }
  float bx[2][4];
  float sc2[2] = {-1.f, -1.f};
  bool valid2[2] = {false, false};
#pragma unroll
  for (int s = 0; s < 2; ++s) {
    int i = t + s * 1024;
    bx[s][0] = bx[s][1] = bx[s][2] = bx[s][3] = 0.f;
    if (i < PRE_K) {
      unsigned long long v = sk[i];
      unsigned int idx = ~(unsigned int)(v & 0xFFFFFFFFull);
      float4 p = *(const float4*)(prop + (size_t)idx * 4);
      float x0 = fminf(fmaxf(p.x, 0.f), IMG_SZ);
      float y0 = fminf(fmaxf(p.y, 0.f), IMG_SZ);
      float x1 = fminf(fmaxf(p.z, 0.f), IMG_SZ);
      float y1 = fminf(fmaxf(p.w, 0.f), IMG_SZ);
      bool valid = (x1 - x0 >= MIN_SZ) && (y1 - y0 >= MIN_SZ);
      bx[s][0] = x0; bx[s][1] = y0; bx[s][2] = x1; bx[s][3] = y1;
      valid2[s] = valid;
      sc2[s] = valid ? score[idx] : -1.0f;
    }
  }
  __syncthreads();
  int* A = (int*)sk;
  int* B = A + 2048;
#pragma unroll
  for (int s = 0; s < 2; ++s) {
    int i = t + s * 1024;
    A[i] = (i < PRE_K && valid2[s]) ? 1 : 0;
  }
  __syncthreads();
  for (int off = 1; off < 2048; off <<= 1) {
#pragma unroll
    for (int s = 0; s < 2; ++s) {
      int i = t + s * 1024;
      B[i] = A[i] + ((i >= off) ? A[i - off] : 0);
    }
    __syncthreads();
    int* tmp = A; A = B; B = tmp;
  }
  int total = A[2047];
#pragma unroll
  for (int s = 0; s < 2; ++s) {
    int i = t + s * 1024;
    if (i < PRE_K) {
      int inc = A[i];
      int pos = valid2[s] ? (inc - 1) : (total + (i - inc));
      boxes_s[pos * 4 + 0] = bx[s][0];
      boxes_s[pos * 4 + 1] = bx[s][1];
      boxes_s[pos * 4 + 2] = bx[s][2];
      boxes_s[pos * 4 + 3] = bx[s][3];
      sc_s[pos] = sc2[s];
    }
  }
}

// =====================================================================
// IoU suppression bitmask
// =====================================================================
__global__ __launch_bounds__(64) void iou_kernel(
    const float* __restrict__ boxes_s, unsigned long long* __restrict__ mask) {
  int bi = blockIdx.y, bj = blockIdx.x;
  int t = threadIdx.x;
  __shared__ float4 cb[64];
  int jc = bj * 64 + t;
  float4 z; z.x = z.y = z.z = z.w = 0.f;
  cb[t] = (jc < PRE_K) ? *(const float4*)(boxes_s + (size_t)jc * 4) : z;
  __syncthreads();
  int i = bi * 64 + t;
  if (i >= PRE_K) return;
  float4 a = *(const float4*)(boxes_s + (size_t)i * 4);
  float areaA = (a.z - a.x) * (a.w - a.y);
  unsigned long long bits = 0ull;
  for (int jj = 0; jj < 64; ++jj) {
    int j = bj * 64 + jj;
    if (j < PRE_K && j > i) {
      float4 b = cb[jj];
      float areaB = (b.z - b.x) * (b.w - b.y);
      float ltx = fmaxf(a.x, b.x), lty = fmaxf(a.y, b.y);
      float rbx = fminf(a.z, b.z), rby = fminf(a.w, b.w);
      float w = fmaxf(rbx - ltx, 0.f), h = fmaxf(rby - lty, 0.f);
      float inter = w * h;
      float iou = inter / (areaA + areaB - inter + 1e-9f);
      if (iou > NMS_TH) bits |= (1ull << jj);
    }
  }
  mask[(size_t)i * 32 + bj] = bits;
}

// =====================================================================
// Sequential NMS scan + final compaction to d_out
// =====================================================================
__global__ __launch_bounds__(1024) void nms_out_kernel(
    const float* __restrict__ boxes_s, const float* __restrict__ sc_s,
    const unsigned long long* __restrict__ mask, float* __restrict__ out) {
  int t = threadIdx.x;
  for (int e = t; e < (OUT_K * 4 + OUT_K); e += 1024) out[e] = 0.f;
  __shared__ unsigned long long keepw[32];
  if (t < 64) {
    int lane = t;
    unsigned long long removed = 0ull;
    if (lane < 32) {
      for (int k = 0; k < 64; ++k) {
        int idx = lane * 64 + k;
        if (idx >= PRE_K || sc_s[idx] < 0.f) removed |= (1ull << k);
      }
    }
    unsigned long long nxt = (lane < 32) ? mask[lane] : 0ull;
    for (int i = 0; i < PRE_K; ++i) {
      unsigned long long cur = nxt;
      if (lane < 32 && (i + 1) < PRE_K)
        nxt = mask[(size_t)(i + 1) * 32 + lane];
      unsigned long long ow = __shfl(removed, i >> 6);
      bool alive = ((ow >> (i & 63)) & 1ull) == 0ull;
      if (alive && lane < 32) removed |= cur;
    }
    if (lane < 32) keepw[lane] = ~removed;
  }
  __syncthreads();
  __shared__ unsigned int wbase[32];
  if (t == 0) {
    unsigned int s = 0;
    for (int k = 0; k < 32; ++k) {
      wbase[k] = s;
      s += (unsigned)__popcll(keepw[k]);
    }
  }
  __syncthreads();
  for (int i = t; i < PRE_K; i += 1024) {
    unsigned long long w = keepw[i >> 6];
    if ((w >> (i & 63)) & 1ull) {
      unsigned int pos =
          wbase[i >> 6] +
          (unsigned)__popcll(w & ((1ull << (i & 63)) - 1ull));
      if (pos < OUT_K) {
        out[pos * 4 + 0] = boxes_s[i * 4 + 0];
        out[pos * 4 + 1] = boxes_s[i * 4 + 1];
        out[pos * 4 + 2] = boxes_s[i * 4 + 2];
        out[pos * 4 + 3] = boxes_s[i * 4 + 3];
        out[OUT_K * 4 + pos] = sc_s[i];
      }
    }
  }
}

// =====================================================================
extern "C" void kernel_launch(void* const* d_in, const int* in_sizes, int n_in,
                              void* d_out, int out_size, void* d_ws,
                              size_t ws_size, hipStream_t stream) {
  const float* feat = (const float*)d_in[1];
  const float* convw = (const float*)d_in[2];
  const float* convb = (const float*)d_in[3];
  const float* clsw = (const float*)d_in[4];
  const float* clsb = (const float*)d_in[5];
  const float* regw = (const float*)d_in[6];
  const float* regb = (const float*)d_in[7];

  char* ws = (char*)d_ws;
  float* logits = (float*)(ws + OFF_LOGIT);
  unsigned int* hist = (unsigned int*)(ws + OFF_HIST);
  unsigned int* state = (unsigned int*)(ws + OFF_STATE);
  unsigned long long* cand = (unsigned long long*)(ws + OFF_CAND);
  float* boxes_s = (float*)(ws + OFF_BOXS);
  float* sc_s = (float*)(ws + OFF_SCS);
  unsigned long long* mask = (unsigned long long*)(ws + OFF_MASK);
  uint4* AW_h = (uint4*)(ws + OFF_AWH);
  uint4* AW_m = (uint4*)(ws + OFF_AWM);
  uint4* AW_l = (uint4*)(ws + OFF_AWL);
  uint4* HwF_h = (uint4*)(ws + OFF_HWH);
  uint4* HwF_m = (uint4*)(ws + OFF_HWM);
  uint4* HwF_l = (uint4*)(ws + OFF_HWL);
  float* prop = (float*)(ws + OFF_PROP);
  float* score = (float*)(ws + OFF_SCORE);
  float* out = (float*)d_out;

  // zero logits + hist + state (contiguous prefix)
  hipMemsetAsync(ws, 0, OFF_STATE + 64, stream);

  prep_weights<<<294, 256, 0, stream>>>(convw, clsw, regw, AW_h, AW_m, AW_l,
                                        HwF_h, HwF_m, HwF_l);
  conv_mfma<<<dim3(13, 25, 2), 256, 0, stream>>>(feat, AW_h, AW_m, AW_l,
                                                 HwF_h, HwF_m, HwF_l, convb,
                                                 logits);
  finalize_kernel<<<157, 256, 0, stream>>>(logits, clsb, regb, prop, score);
  for (int p = 0; p < 4; ++p) {
    hist_kernel<<<256, 256, 0, stream>>>(score, hist, state, p);
    scan_kernel<<<1, 256, 0, stream>>>(hist, state, p);
  }
  collect_kernel<<<256, 256, 0, stream>>>(score, state, cand);
  sort_gather<<<1, 1024, 0, stream>>>(cand, state, prop, score, boxes_s, sc_s);
  iou_kernel<<<dim3(32, 32), 64, 0, stream>>>(boxes_s, mask);
  nms_out_kernel<<<1, 1024, 0, stream>>>(boxes_s, sc_s, mask, out);
}

// Round 5
// 1005.291 us; speedup vs baseline: 1.8281x; 1.0851x over previous
//
#include <hip/hip_runtime.h>
#include <math.h>

// ---------------- constants ----------------
#define FH 200
#define FW 200
#define HW 40000            // FH*FW
#define NUM_A 9
#define NANCH 360000        // HW*NUM_A
#define PRE_K 2000
#define OUT_K 1000
#define IMG_SZ 1600.0f
#define MIN_SZ 16.0f
#define NMS_TH 0.7f
#define BBOX_CLIP_F 4.135166556742356f   // log(1000/16)

// ---------------- workspace layout (bytes), total ~18.6 MB ----------------
#define OFF_LOGIT  ((size_t)0)           // 40000*45*4 = 7,200,000
#define OFF_HIST   ((size_t)7200000)     // 256 u32 = 1024
#define OFF_STATE  ((size_t)7201024)     // 16 u32 = 64
#define OFF_CAND   ((size_t)7201088)     // 4096 u64 = 32,768
#define OFF_BOXS   ((size_t)7233856)     // 2000*4 f = 32,000
#define OFF_SCS    ((size_t)7265856)     // 2000 f = 8,000
#define OFF_MASK   ((size_t)7273856)     // 2000*32 u64 = 512,000
#define OFF_AWH    ((size_t)7785856)     // 16*9*8*64*16B = 1,179,648
#define OFF_AWM    ((size_t)8965504)
#define OFF_AWL    ((size_t)10145152)
#define OFF_HWH    ((size_t)11324800)    // 3*8*64*16B = 24,576
#define OFF_HWM    ((size_t)11349376)
#define OFF_HWL    ((size_t)11373952)
#define OFF_PROP   ((size_t)11398528)    // 360000*4 f = 5,760,000
#define OFF_SCORE  ((size_t)17158528)    // 360000 f = 1,440,000 -> 18,598,528

typedef __attribute__((ext_vector_type(8))) short short8;
typedef __attribute__((ext_vector_type(4))) float floatx4;
#define MFMA16(a, b, c) __builtin_amdgcn_mfma_f32_16x16x32_bf16(a, b, c, 0, 0, 0)

__device__ __forceinline__ unsigned short rne_bf16(float v) {
  unsigned int bb = __float_as_uint(v);
  return (unsigned short)((bb + 0x7FFFu + ((bb >> 16) & 1u)) >> 16);
}

// 3-way split: v = h + m + l + eps, |eps| <~ 2^-25 |v|
__device__ __forceinline__ void split3(float v, unsigned short& h,
                                       unsigned short& m, unsigned short& l) {
  h = rne_bf16(v);
  float r1 = v - __uint_as_float(((unsigned int)h) << 16);
  m = rne_bf16(r1);
  float r2 = r1 - __uint_as_float(((unsigned int)m) << 16);
  l = rne_bf16(r2);
}

// =====================================================================
// Prepass: swizzle conv weights + head weights into MFMA A-fragment
// order (lane L of tile ctg holds W[ctg*16+(L&15)][k=cib*32+(L>>4)*8+j]),
// 3-way bf16 split (hi/mid/lo planes).
// =====================================================================
__global__ __launch_bounds__(256) void prep_weights(
    const float* __restrict__ w, const float* __restrict__ cls_w,
    const float* __restrict__ reg_w, uint4* __restrict__ AW_h,
    uint4* __restrict__ AW_m, uint4* __restrict__ AW_l,
    uint4* __restrict__ HwF_h, uint4* __restrict__ HwF_m,
    uint4* __restrict__ HwF_l) {
  int gid = blockIdx.x * 256 + threadIdx.x;
  unsigned short h[8], m[8], l[8];
  if (gid < 73728) {
    int L = gid & 63;
    int idx = gid >> 6;            // (ctg*9+tap)*8 + cib
    int cib = idx & 7;
    int tmp = idx >> 3;
    int tap = tmp % 9;
    int ctg = tmp / 9;
    int co = ctg * 16 + (L & 15);
    int ci0 = cib * 32 + (L >> 4) * 8;
#pragma unroll
    for (int j = 0; j < 8; ++j)
      split3(w[(size_t)co * 2304 + (ci0 + j) * 9 + tap], h[j], m[j], l[j]);
    uint4 vh, vm, vl;
    vh.x = h[0] | (h[1] << 16); vh.y = h[2] | (h[3] << 16);
    vh.z = h[4] | (h[5] << 16); vh.w = h[6] | (h[7] << 16);
    vm.x = m[0] | (m[1] << 16); vm.y = m[2] | (m[3] << 16);
    vm.z = m[4] | (m[5] << 16); vm.w = m[6] | (m[7] << 16);
    vl.x = l[0] | (l[1] << 16); vl.y = l[2] | (l[3] << 16);
    vl.z = l[4] | (l[5] << 16); vl.w = l[6] | (l[7] << 16);
    AW_h[gid] = vh; AW_m[gid] = vm; AW_l[gid] = vl;
  } else if (gid < 73728 + 1536) {
    int g2 = gid - 73728;
    int L = g2 & 63;
    int idx = g2 >> 6;             // mt*8 + kb
    int kb = idx & 7;
    int mt = idx >> 3;
    int mm = mt * 16 + (L & 15);
    int co0 = kb * 32 + (L >> 4) * 8;
#pragma unroll
    for (int j = 0; j < 8; ++j) {
      float v = 0.f;
      if (mm < 9) v = cls_w[mm * 256 + co0 + j];
      else if (mm < 45) v = reg_w[(mm - 9) * 256 + co0 + j];
      split3(v, h[j], m[j], l[j]);
    }
    uint4 vh, vm, vl;
    vh.x = h[0] | (h[1] << 16); vh.y = h[2] | (h[3] << 16);
    vh.z = h[4] | (h[5] << 16); vh.w = h[6] | (h[7] << 16);
    vm.x = m[0] | (m[1] << 16); vm.y = m[2] | (m[3] << 16);
    vm.z = m[4] | (m[5] << 16); vm.w = m[6] | (m[7] << 16);
    vl.x = l[0] | (l[1] << 16); vl.y = l[2] | (l[3] << 16);
    vl.z = l[4] | (l[5] << 16); vl.w = l[6] | (l[7] << 16);
    HwF_h[g2] = vh; HwF_m[g2] = vm; HwF_l[g2] = vl;
  }
}

// =====================================================================
// Main conv+heads MFMA kernel (3-way split, 6 products ~= fp32 accuracy).
// Block tile: 128 co (cb half) x 128 px (8 rows x 16 cols).
// =====================================================================
__global__ __launch_bounds__(256) void conv_mfma(
    const float* __restrict__ feat, const uint4* __restrict__ AW_h,
    const uint4* __restrict__ AW_m, const uint4* __restrict__ AW_l,
    const uint4* __restrict__ HwF_h, const uint4* __restrict__ HwF_m,
    const uint4* __restrict__ HwF_l, const float* __restrict__ bias,
    float* __restrict__ logits) {
  __shared__ alignas(16) unsigned short smem[26112];  // 52,224 B
  const int t = threadIdx.x;
  const int L = t & 63, wv = t >> 6;
  const int q = L >> 4, nl = L & 15;
  const int w0 = blockIdx.x * 16;
  const int h0 = blockIdx.y * 8;
  const int cb = blockIdx.z;

  floatx4 acc[2][8];
#pragma unroll
  for (int ct = 0; ct < 2; ++ct)
#pragma unroll
    for (int r = 0; r < 8; ++r) acc[ct][r] = (floatx4)0.f;

  unsigned short* flh = smem;          // [10 rows][18 cols][40 ci-pad] u16
  unsigned short* flm = smem + 7200;
  unsigned short* fll = smem + 14400;

  for (int cib = 0; cib < 8; ++cib) {
    __syncthreads();
#pragma unroll
    for (int j = 0; j < 23; ++j) {
      int e = j * 256 + t;
      if (e < 5760) {
        int ci = e / 180;
        int rem = e - ci * 180;
        int rr = rem / 18;
        int cc = rem - rr * 18;
        int gr = h0 - 1 + rr, gc = w0 - 1 + cc;
        float v = 0.f;
        if ((unsigned)gr < (unsigned)FH && (unsigned)gc < (unsigned)FW)
          v = feat[(size_t)(cib * 32 + ci) * HW + gr * FW + gc];
        unsigned short hh, mm, ll;
        split3(v, hh, mm, ll);
        int off = rr * 720 + cc * 40 + ci;
        flh[off] = hh; flm[off] = mm; fll[off] = ll;
      }
    }
    __syncthreads();
    const int ctg0 = cb * 8 + wv * 2;
    for (int kh = 0; kh < 3; ++kh) {
      for (int kw = 0; kw < 3; ++kw) {
        const int tap = kh * 3 + kw;
        const int abase = ((ctg0 * 9 + tap) * 8 + cib) * 64 + L;
        const int abase1 = abase + 9 * 8 * 64;
        short8 ah0 = ((const short8*)AW_h)[abase];
        short8 am0 = ((const short8*)AW_m)[abase];
        short8 al0 = ((const short8*)AW_l)[abase];
        short8 ah1 = ((const short8*)AW_h)[abase1];
        short8 am1 = ((const short8*)AW_m)[abase1];
        short8 al1 = ((const short8*)AW_l)[abase1];
        const int cbase = (nl + kw) * 40 + q * 8;
#pragma unroll
        for (int r = 0; r < 8; ++r) {
          const int off = (r + kh) * 720 + cbase;
          short8 bh = *(const short8*)(flh + off);
          short8 bm = *(const short8*)(flm + off);
          short8 bl = *(const short8*)(fll + off);
          acc[0][r] = MFMA16(ah0, bh, acc[0][r]);
          acc[0][r] = MFMA16(ah0, bm, acc[0][r]);
          acc[0][r] = MFMA16(am0, bh, acc[0][r]);
          acc[0][r] = MFMA16(ah0, bl, acc[0][r]);
          acc[0][r] = MFMA16(am0, bm, acc[0][r]);
          acc[0][r] = MFMA16(al0, bh, acc[0][r]);
          acc[1][r] = MFMA16(ah1, bh, acc[1][r]);
          acc[1][r] = MFMA16(ah1, bm, acc[1][r]);
          acc[1][r] = MFMA16(am1, bh, acc[1][r]);
          acc[1][r] = MFMA16(ah1, bl, acc[1][r]);
          acc[1][r] = MFMA16(am1, bm, acc[1][r]);
          acc[1][r] = MFMA16(al1, bh, acc[1][r]);
        }
      }
    }
  }

  // ---- epilogue ----
  float bv[2][4];
#pragma unroll
  for (int ct = 0; ct < 2; ++ct)
#pragma unroll
    for (int i = 0; i < 4; ++i)
      bv[ct][i] = bias[cb * 128 + (wv * 2 + ct) * 16 + q * 4 + i];

  unsigned short* xlh = smem;           // [64 px][136 co-pad] u16
  unsigned short* xlm = smem + 8704;
  unsigned short* xll = smem + 17408;

  for (int hp = 0; hp < 2; ++hp) {
    __syncthreads();
#pragma unroll
    for (int ct = 0; ct < 2; ++ct) {
#pragma unroll
      for (int rr = 0; rr < 4; ++rr) {
        int r = hp * 4 + rr;
        unsigned short xh[4], xm[4], xl_[4];
#pragma unroll
        for (int i = 0; i < 4; ++i) {
          float xv = fmaxf(acc[ct][r][i] + bv[ct][i], 0.f);
          split3(xv, xh[i], xm[i], xl_[i]);
        }
        int px_l = rr * 16 + nl;
        int co_l = (wv * 2 + ct) * 16 + q * 4;
        uint2 ph, pm, pl;
        ph.x = xh[0] | (xh[1] << 16); ph.y = xh[2] | (xh[3] << 16);
        pm.x = xm[0] | (xm[1] << 16); pm.y = xm[2] | (xm[3] << 16);
        pl.x = xl_[0] | (xl_[1] << 16); pl.y = xl_[2] | (xl_[3] << 16);
        *(uint2*)(xlh + px_l * 136 + co_l) = ph;
        *(uint2*)(xlm + px_l * 136 + co_l) = pm;
        *(uint2*)(xll + px_l * 136 + co_l) = pl;
      }
    }
    __syncthreads();
    floatx4 ha[3];
#pragma unroll
    for (int mt = 0; mt < 3; ++mt) ha[mt] = (floatx4)0.f;
    for (int ks = 0; ks < 4; ++ks) {
      const int off = (wv * 16 + nl) * 136 + ks * 32 + q * 8;
      short8 bh = *(const short8*)(xlh + off);
      short8 bm = *(const short8*)(xlm + off);
      short8 bl = *(const short8*)(xll + off);
#pragma unroll
      for (int mt = 0; mt < 3; ++mt) {
        const int hb = (mt * 8 + cb * 4 + ks) * 64 + L;
        short8 hh = ((const short8*)HwF_h)[hb];
        short8 hm = ((const short8*)HwF_m)[hb];
        short8 hl = ((const short8*)HwF_l)[hb];
        ha[mt] = MFMA16(hh, bh, ha[mt]);
        ha[mt] = MFMA16(hh, bm, ha[mt]);
        ha[mt] = MFMA16(hm, bh, ha[mt]);
        ha[mt] = MFMA16(hh, bl, ha[mt]);
        ha[mt] = MFMA16(hm, bm, ha[mt]);
        ha[mt] = MFMA16(hl, bh, ha[mt]);
      }
    }
    int gr = h0 + hp * 4 + wv;
    int gc = w0 + nl;
    if (gc < FW) {
#pragma unroll
      for (int mt = 0; mt < 3; ++mt)
#pragma unroll
        for (int i = 0; i < 4; ++i) {
          int head = mt * 16 + q * 4 + i;
          if (head < 45)
            atomicAdd(&logits[(size_t)(gr * FW + gc) * 45 + head], ha[mt][i]);
        }
    }
  }
}

// =====================================================================
// finalize — bias + anchors + deltas + sigmoid from logits
// =====================================================================
__global__ __launch_bounds__(256) void finalize_kernel(
    const float* __restrict__ logits, const float* __restrict__ cls_b,
    const float* __restrict__ reg_b, float* __restrict__ prop,
    float* __restrict__ score) {
  int px = blockIdx.x * 256 + threadIdx.x;
  if (px >= HW) return;
  float A[45];
  const float* lp = logits + (size_t)px * 45;
#pragma unroll
  for (int i = 0; i < 45; ++i) A[i] = lp[i];
  const float scv[3] = {128.f, 256.f, 512.f};
  const float arv[3] = {0.5f, 1.f, 2.f};
  float sx = (float)(px % FW) * 8.0f;
  float sy = (float)(px / FW) * 8.0f;
#pragma unroll
  for (int a = 0; a < NUM_A; ++a) {
    int ai = a / 3, si = a % 3;
    float hr = sqrtf(arv[ai]);
    float wr = 1.0f / hr;
    float rw = nearbyintf(wr * scv[si] * 0.5f);
    float rh = nearbyintf(hr * scv[si] * 0.5f);
    float ax0 = sx - rw, ay0 = sy - rh, ax1 = sx + rw, ay1 = sy + rh;
    float aw = ax1 - ax0, ah = ay1 - ay0;
    float cx = ax0 + 0.5f * aw, cy = ay0 + 0.5f * ah;
    float dx = A[9 + a * 4 + 0] + reg_b[a * 4 + 0];
    float dy = A[9 + a * 4 + 1] + reg_b[a * 4 + 1];
    float dw = fminf(A[9 + a * 4 + 2] + reg_b[a * 4 + 2], BBOX_CLIP_F);
    float dh = fminf(A[9 + a * 4 + 3] + reg_b[a * 4 + 3], BBOX_CLIP_F);
    float pcx = dx * aw + cx;
    float pcy = dy * ah + cy;
    float pw = expf(dw) * aw;
    float ph = expf(dh) * ah;
    size_t base = (size_t)(px * NUM_A + a) * 4;
    prop[base + 0] = pcx - 0.5f * pw;
    prop[base + 1] = pcy - 0.5f * ph;
    prop[base + 2] = pcx + 0.5f * pw;
    prop[base + 3] = pcy + 0.5f * ph;
    float lg = A[a] + cls_b[a];
    score[px * NUM_A + a] = 1.0f / (1.0f + expf(-lg));
  }
}

// =====================================================================
// Radix select (4 passes of 8 bits) for exact top-2000 threshold
// =====================================================================
__global__ __launch_bounds__(256) void hist_kernel(
    const float* __restrict__ score, unsigned int* __restrict__ hist,
    const unsigned int* __restrict__ state, int pass) {
  __shared__ unsigned int h[256];
  int t = threadIdx.x;
  h[t] = 0;
  __syncthreads();
  unsigned int prefix = (pass == 0) ? 0u : state[0];
  int shift = 24 - 8 * pass;
  for (int i = blockIdx.x * 256 + t; i < NANCH; i += gridDim.x * 256) {
    unsigned int key = __float_as_uint(score[i]);
    bool m = (pass == 0) || ((key >> (32 - 8 * pass)) == prefix);
    if (m) atomicAdd(&h[(key >> shift) & 255u], 1u);
  }
  __syncthreads();
  if (h[t]) atomicAdd(&hist[t], h[t]);
}

__global__ __launch_bounds__(256) void scan_kernel(
    unsigned int* __restrict__ hist, unsigned int* __restrict__ state, int pass) {
  __shared__ unsigned int s0[256], s1[256];
  int t = threadIdx.x;
  unsigned int hv = hist[t];
  hist[t] = 0u;
  s0[t] = hv;
  __syncthreads();
  unsigned int* A = s0;
  unsigned int* B = s1;
  for (int off = 1; off < 256; off <<= 1) {
    B[t] = A[t] + ((t + off < 256) ? A[t + off] : 0u);
    __syncthreads();
    unsigned int* tmp = A; A = B; B = tmp;
  }
  unsigned int prefix = (pass == 0) ? 0u : state[0];
  unsigned int rem = (pass == 0) ? (unsigned)PRE_K : state[1];
  unsigned int suf = A[t];
  unsigned int sufn = (t < 255) ? A[t + 1] : 0u;
  if (suf >= rem && sufn < rem) {
    state[0] = (prefix << 8) | (unsigned int)t;
    state[1] = rem - sufn;
  }
}

__global__ __launch_bounds__(256) void collect_kernel(
    const float* __restrict__ score, unsigned int* __restrict__ state,
    unsigned long long* __restrict__ cand) {
  unsigned int T = state[0];
  for (int i = blockIdx.x * 256 + threadIdx.x; i < NANCH; i += gridDim.x * 256) {
    unsigned int key = __float_as_uint(score[i]);
    if (key >= T) {
      unsigned int pos = atomicAdd(&state[4], 1u);
      if (pos < 4096u)
        cand[pos] = ((unsigned long long)key << 32) |
                    (unsigned long long)(~(unsigned int)i);
    }
  }
}

// =====================================================================
// Bitonic sort + gather + clip + valid + stable partition
// =====================================================================
__global__ __launch_bounds__(1024) void sort_gather(
    const unsigned long long* __restrict__ cand,
    const unsigned int* __restrict__ state, const float* __restrict__ prop,
    const float* __restrict__ score, float* __restrict__ boxes_s,
    float* __restrict__ sc_s) {
  __shared__ unsigned long long sk[4096];
  int t = threadIdx.x;
  unsigned int cnt = state[4];
  if (cnt > 4096u) cnt = 4096u;
  for (int e = t; e < 4096; e += 1024) sk[e] = (e < (int)cnt) ? cand[e] : 0ull;
  __syncthreads();
  for (int k = 2; k <= 4096; k <<= 1) {
    for (int j = k >> 1; j > 0; j >>= 1) {
      for (int i = t; i < 4096; i += 1024) {
        int l = i ^ j;
        if (l > i) {
          unsigned long long a = sk[i], bb = sk[l];
          bool up = ((i & k) == 0);
          bool sw = up ? (a < bb) : (a > bb);
          if (sw) { sk[i] = bb; sk[l] = a; }
        }
      }
      __syncthreads();
    }
  }
  float bx[2][4];
  float sc2[2] = {-1.f, -1.f};
  bool valid2[2] = {false, false};
#pragma unroll
  for (int s = 0; s < 2; ++s) {
    int i = t + s * 1024;
    bx[s][0] = bx[s][1] = bx[s][2] = bx[s][3] = 0.f;
    if (i < PRE_K) {
      unsigned long long v = sk[i];
      unsigned int idx = ~(unsigned int)(v & 0xFFFFFFFFull);
      float4 p = *(const float4*)(prop + (size_t)idx * 4);
      float x0 = fminf(fmaxf(p.x, 0.f), IMG_SZ);
      float y0 = fminf(fmaxf(p.y, 0.f), IMG_SZ);
      float x1 = fminf(fmaxf(p.z, 0.f), IMG_SZ);
      float y1 = fminf(fmaxf(p.w, 0.f), IMG_SZ);
      bool valid = (x1 - x0 >= MIN_SZ) && (y1 - y0 >= MIN_SZ);
      bx[s][0] = x0; bx[s][1] = y0; bx[s][2] = x1; bx[s][3] = y1;
      valid2[s] = valid;
      sc2[s] = valid ? score[idx] : -1.0f;
    }
  }
  __syncthreads();
  int* A = (int*)sk;
  int* B = A + 2048;
#pragma unroll
  for (int s = 0; s < 2; ++s) {
    int i = t + s * 1024;
    A[i] = (i < PRE_K && valid2[s]) ? 1 : 0;
  }
  __syncthreads();
  for (int off = 1; off < 2048; off <<= 1) {
#pragma unroll
    for (int s = 0; s < 2; ++s) {
      int i = t + s * 1024;
      B[i] = A[i] + ((i >= off) ? A[i - off] : 0);
    }
    __syncthreads();
    int* tmp = A; A = B; B = tmp;
  }
  int total = A[2047];
#pragma unroll
  for (int s = 0; s < 2; ++s) {
    int i = t + s * 1024;
    if (i < PRE_K) {
      int inc = A[i];
      int pos = valid2[s] ? (inc - 1) : (total + (i - inc));
      boxes_s[pos * 4 + 0] = bx[s][0];
      boxes_s[pos * 4 + 1] = bx[s][1];
      boxes_s[pos * 4 + 2] = bx[s][2];
      boxes_s[pos * 4 + 3] = bx[s][3];
      sc_s[pos] = sc2[s];
    }
  }
}

// =====================================================================
// IoU suppression bitmask
// =====================================================================
__global__ __launch_bounds__(64) void iou_kernel(
    const float* __restrict__ boxes_s, unsigned long long* __restrict__ mask) {
  int bi = blockIdx.y, bj = blockIdx.x;
  int t = threadIdx.x;
  __shared__ float4 cb[64];
  int jc = bj * 64 + t;
  float4 z; z.x = z.y = z.z = z.w = 0.f;
  cb[t] = (jc < PRE_K) ? *(const float4*)(boxes_s + (size_t)jc * 4) : z;
  __syncthreads();
  int i = bi * 64 + t;
  if (i >= PRE_K) return;
  float4 a = *(const float4*)(boxes_s + (size_t)i * 4);
  float areaA = (a.z - a.x) * (a.w - a.y);
  unsigned long long bits = 0ull;
  for (int jj = 0; jj < 64; ++jj) {
    int j = bj * 64 + jj;
    if (j < PRE_K && j > i) {
      float4 b = cb[jj];
      float areaB = (b.z - b.x) * (b.w - b.y);
      float ltx = fmaxf(a.x, b.x), lty = fmaxf(a.y, b.y);
      float rbx = fminf(a.z, b.z), rby = fminf(a.w, b.w);
      float w = fmaxf(rbx - ltx, 0.f), h = fmaxf(rby - lty, 0.f);
      float inter = w * h;
      float iou = inter / (areaA + areaB - inter + 1e-9f);
      if (iou > NMS_TH) bits |= (1ull << jj);
    }
  }
  mask[(size_t)i * 32 + bj] = bits;
}

// =====================================================================
// Block-resolved sequential NMS + final compaction to d_out.
// 32 blocks of 64 candidates.  Per block: lane k holds the diag mask word
// of row b*64+k (one coalesced load, off the serial chain); aliveness is
// resolved with a 64-step in-register shfl chain (~3 VALU/step); then the
// block's alive rows' suppression is OR-ed into future words with parallel
// coalesced loads across 32 word-owner lanes.  Semantics == greedy scan.
// =====================================================================
__global__ __launch_bounds__(256) void nms_out_kernel(
    const float* __restrict__ boxes_s, const float* __restrict__ sc_s,
    const unsigned long long* __restrict__ mask, float* __restrict__ out) {
  int t = threadIdx.x;
  for (int e = t; e < (OUT_K * 4 + OUT_K); e += 256) out[e] = 0.f;
  __shared__ unsigned long long keepw[32];
  if (t < 64) {
    unsigned long long removed = 0ull;  // lanes 0..31: removed bits of word t
    if (t < 32) {
#pragma unroll
      for (int k = 0; k < 64; ++k) {
        int idx = t * 64 + k;
        if (idx >= PRE_K || sc_s[idx] < 0.f) removed |= (1ull << k);
      }
    }
    for (int b = 0; b < 32; ++b) {
      int row = b * 64 + t;
      unsigned long long d =
          (row < PRE_K) ? mask[(size_t)row * 32 + b] : 0ull;
      unsigned long long dead = __shfl(removed, b);
      unsigned long long alive = 0ull;
#pragma unroll
      for (int k = 0; k < 64; ++k) {
        unsigned long long dk = __shfl(d, k);
        if (!((dead >> k) & 1ull)) {
          alive |= (1ull << k);
          dead |= dk;
        }
      }
      if (t < 32) {
        unsigned long long am = alive;
        while (am) {
          int k = __ffsll((unsigned long long)am) - 1;
          am &= am - 1;
          removed |= mask[(size_t)(b * 64 + k) * 32 + t];
        }
      }
      if (t == 0) keepw[b] = alive;
    }
  }
  __syncthreads();
  __shared__ unsigned int wbase[32];
  if (t == 0) {
    unsigned int s = 0;
    for (int k = 0; k < 32; ++k) {
      wbase[k] = s;
      s += (unsigned)__popcll(keepw[k]);
    }
  }
  __syncthreads();
  for (int i = t; i < PRE_K; i += 256) {
    unsigned long long w = keepw[i >> 6];
    if ((w >> (i & 63)) & 1ull) {
      unsigned int pos =
          wbase[i >> 6] +
          (unsigned)__popcll(w & ((1ull << (i & 63)) - 1ull));
      if (pos < OUT_K) {
        out[pos * 4 + 0] = boxes_s[i * 4 + 0];
        out[pos * 4 + 1] = boxes_s[i * 4 + 1];
        out[pos * 4 + 2] = boxes_s[i * 4 + 2];
        out[pos * 4 + 3] = boxes_s[i * 4 + 3];
        out[OUT_K * 4 + pos] = sc_s[i];
      }
    }
  }
}

// =====================================================================
extern "C" void kernel_launch(void* const* d_in, const int* in_sizes, int n_in,
                              void* d_out, int out_size, void* d_ws,
                              size_t ws_size, hipStream_t stream) {
  const float* feat = (const float*)d_in[1];
  const float* convw = (const float*)d_in[2];
  const float* convb = (const float*)d_in[3];
  const float* clsw = (const float*)d_in[4];
  const float* clsb = (const float*)d_in[5];
  const float* regw = (const float*)d_in[6];
  const float* regb = (const float*)d_in[7];

  char* ws = (char*)d_ws;
  float* logits = (float*)(ws + OFF_LOGIT);
  unsigned int* hist = (unsigned int*)(ws + OFF_HIST);
  unsigned int* state = (unsigned int*)(ws + OFF_STATE);
  unsigned long long* cand = (unsigned long long*)(ws + OFF_CAND);
  float* boxes_s = (float*)(ws + OFF_BOXS);
  float* sc_s = (float*)(ws + OFF_SCS);
  unsigned long long* mask = (unsigned long long*)(ws + OFF_MASK);
  uint4* AW_h = (uint4*)(ws + OFF_AWH);
  uint4* AW_m = (uint4*)(ws + OFF_AWM);
  uint4* AW_l = (uint4*)(ws + OFF_AWL);
  uint4* HwF_h = (uint4*)(ws + OFF_HWH);
  uint4* HwF_m = (uint4*)(ws + OFF_HWM);
  uint4* HwF_l = (uint4*)(ws + OFF_HWL);
  float* prop = (float*)(ws + OFF_PROP);
  float* score = (float*)(ws + OFF_SCORE);
  float* out = (float*)d_out;

  // zero logits + hist + state (contiguous prefix)
  hipMemsetAsync(ws, 0, OFF_STATE + 64, stream);

  prep_weights<<<294, 256, 0, stream>>>(convw, clsw, regw, AW_h, AW_m, AW_l,
                                        HwF_h, HwF_m, HwF_l);
  conv_mfma<<<dim3(13, 25, 2), 256, 0, stream>>>(feat, AW_h, AW_m, AW_l,
                                                 HwF_h, HwF_m, HwF_l, convb,
                                                 logits);
  finalize_kernel<<<157, 256, 0, stream>>>(logits, clsb, regb, prop, score);
  for (int p = 0; p < 4; ++p) {
    hist_kernel<<<256, 256, 0, stream>>>(score, hist, state, p);
    scan_kernel<<<1, 256, 0, stream>>>(hist, state, p);
  }
  collect_kernel<<<256, 256, 0, stream>>>(score, state, cand);
  sort_gather<<<1, 1024, 0, stream>>>(cand, state, prop, score, boxes_s, sc_s);
  iou_kernel<<<dim3(32, 32), 64, 0, stream>>>(boxes_s, mask);
  nms_out_kernel<<<256, 256, 0, stream>>>(boxes_s, sc_s, mask, out);
}

// Round 6
// 727.754 us; speedup vs baseline: 2.5253x; 1.3814x over previous
//
#include <hip/hip_runtime.h>
#include <math.h>

// ---------------- constants ----------------
#define FH 200
#define FW 200
#define HW 40000            // FH*FW
#define NUM_A 9
#define NANCH 360000        // HW*NUM_A
#define PRE_K 2000
#define OUT_K 1000
#define IMG_SZ 1600.0f
#define MIN_SZ 16.0f
#define NMS_TH 0.7f
#define BBOX_CLIP_F 4.135166556742356f   // log(1000/16)

// ---------------- workspace layout (bytes), total ~18.6 MB ----------------
#define OFF_LOGIT  ((size_t)0)           // 40000*45*4 = 7,200,000
#define OFF_HIST   ((size_t)7200000)     // 256 u32 = 1024
#define OFF_STATE  ((size_t)7201024)     // 16 u32 = 64
#define OFF_CAND   ((size_t)7201088)     // 4096 u64 = 32,768
#define OFF_BOXS   ((size_t)7233856)     // 2000*4 f = 32,000
#define OFF_SCS    ((size_t)7265856)     // 2000 f = 8,000
#define OFF_MASK   ((size_t)7273856)     // 2000*32 u64 = 512,000
#define OFF_AWH    ((size_t)7785856)     // 16*9*8*64*16B = 1,179,648
#define OFF_AWM    ((size_t)8965504)
#define OFF_AWL    ((size_t)10145152)
#define OFF_HWH    ((size_t)11324800)    // 3*8*64*16B = 24,576
#define OFF_HWM    ((size_t)11349376)
#define OFF_HWL    ((size_t)11373952)
#define OFF_PROP   ((size_t)11398528)    // 360000*4 f = 5,760,000
#define OFF_SCORE  ((size_t)17158528)    // 360000 f = 1,440,000
#define OFF_DIAG   ((size_t)18598528)    // 2048 u64 = 16,384 -> 18,614,912

typedef __attribute__((ext_vector_type(8))) short short8;
typedef __attribute__((ext_vector_type(4))) float floatx4;
#define MFMA16(a, b, c) __builtin_amdgcn_mfma_f32_16x16x32_bf16(a, b, c, 0, 0, 0)

__device__ __forceinline__ unsigned short rne_bf16(float v) {
  unsigned int bb = __float_as_uint(v);
  return (unsigned short)((bb + 0x7FFFu + ((bb >> 16) & 1u)) >> 16);
}

// 3-way split: v = h + m + l + eps, |eps| <~ 2^-25 |v|
__device__ __forceinline__ void split3(float v, unsigned short& h,
                                       unsigned short& m, unsigned short& l) {
  h = rne_bf16(v);
  float r1 = v - __uint_as_float(((unsigned int)h) << 16);
  m = rne_bf16(r1);
  float r2 = r1 - __uint_as_float(((unsigned int)m) << 16);
  l = rne_bf16(r2);
}

// =====================================================================
// Prepass: swizzle conv weights + head weights into MFMA A-fragment
// order, 3-way bf16 split (hi/mid/lo planes).
// =====================================================================
__global__ __launch_bounds__(256) void prep_weights(
    const float* __restrict__ w, const float* __restrict__ cls_w,
    const float* __restrict__ reg_w, uint4* __restrict__ AW_h,
    uint4* __restrict__ AW_m, uint4* __restrict__ AW_l,
    uint4* __restrict__ HwF_h, uint4* __restrict__ HwF_m,
    uint4* __restrict__ HwF_l) {
  int gid = blockIdx.x * 256 + threadIdx.x;
  unsigned short h[8], m[8], l[8];
  if (gid < 73728) {
    int L = gid & 63;
    int idx = gid >> 6;            // (ctg*9+tap)*8 + cib
    int cib = idx & 7;
    int tmp = idx >> 3;
    int tap = tmp % 9;
    int ctg = tmp / 9;
    int co = ctg * 16 + (L & 15);
    int ci0 = cib * 32 + (L >> 4) * 8;
#pragma unroll
    for (int j = 0; j < 8; ++j)
      split3(w[(size_t)co * 2304 + (ci0 + j) * 9 + tap], h[j], m[j], l[j]);
    uint4 vh, vm, vl;
    vh.x = h[0] | (h[1] << 16); vh.y = h[2] | (h[3] << 16);
    vh.z = h[4] | (h[5] << 16); vh.w = h[6] | (h[7] << 16);
    vm.x = m[0] | (m[1] << 16); vm.y = m[2] | (m[3] << 16);
    vm.z = m[4] | (m[5] << 16); vm.w = m[6] | (m[7] << 16);
    vl.x = l[0] | (l[1] << 16); vl.y = l[2] | (l[3] << 16);
    vl.z = l[4] | (l[5] << 16); vl.w = l[6] | (l[7] << 16);
    AW_h[gid] = vh; AW_m[gid] = vm; AW_l[gid] = vl;
  } else if (gid < 73728 + 1536) {
    int g2 = gid - 73728;
    int L = g2 & 63;
    int idx = g2 >> 6;             // mt*8 + kb
    int kb = idx & 7;
    int mt = idx >> 3;
    int mm = mt * 16 + (L & 15);
    int co0 = kb * 32 + (L >> 4) * 8;
#pragma unroll
    for (int j = 0; j < 8; ++j) {
      float v = 0.f;
      if (mm < 9) v = cls_w[mm * 256 + co0 + j];
      else if (mm < 45) v = reg_w[(mm - 9) * 256 + co0 + j];
      split3(v, h[j], m[j], l[j]);
    }
    uint4 vh, vm, vl;
    vh.x = h[0] | (h[1] << 16); vh.y = h[2] | (h[3] << 16);
    vh.z = h[4] | (h[5] << 16); vh.w = h[6] | (h[7] << 16);
    vm.x = m[0] | (m[1] << 16); vm.y = m[2] | (m[3] << 16);
    vm.z = m[4] | (m[5] << 16); vm.w = m[6] | (m[7] << 16);
    vl.x = l[0] | (l[1] << 16); vl.y = l[2] | (l[3] << 16);
    vl.z = l[4] | (l[5] << 16); vl.w = l[6] | (l[7] << 16);
    HwF_h[g2] = vh; HwF_m[g2] = vm; HwF_l[g2] = vl;
  }
}

// =====================================================================
// Main conv+heads MFMA kernel (3-way split, 6 products ~= fp32 accuracy).
// Block tile: 128 co (cb half) x 128 px (8 rows x 16 cols).
// =====================================================================
__global__ __launch_bounds__(256) void conv_mfma(
    const float* __restrict__ feat, const uint4* __restrict__ AW_h,
    const uint4* __restrict__ AW_m, const uint4* __restrict__ AW_l,
    const uint4* __restrict__ HwF_h, const uint4* __restrict__ HwF_m,
    const uint4* __restrict__ HwF_l, const float* __restrict__ bias,
    float* __restrict__ logits) {
  __shared__ alignas(16) unsigned short smem[26112];  // 52,224 B
  const int t = threadIdx.x;
  const int L = t & 63, wv = t >> 6;
  const int q = L >> 4, nl = L & 15;
  const int w0 = blockIdx.x * 16;
  const int h0 = blockIdx.y * 8;
  const int cb = blockIdx.z;

  floatx4 acc[2][8];
#pragma unroll
  for (int ct = 0; ct < 2; ++ct)
#pragma unroll
    for (int r = 0; r < 8; ++r) acc[ct][r] = (floatx4)0.f;

  unsigned short* flh = smem;          // [10 rows][18 cols][40 ci-pad] u16
  unsigned short* flm = smem + 7200;
  unsigned short* fll = smem + 14400;

  for (int cib = 0; cib < 8; ++cib) {
    __syncthreads();
#pragma unroll
    for (int j = 0; j < 23; ++j) {
      int e = j * 256 + t;
      if (e < 5760) {
        int ci = e / 180;
        int rem = e - ci * 180;
        int rr = rem / 18;
        int cc = rem - rr * 18;
        int gr = h0 - 1 + rr, gc = w0 - 1 + cc;
        float v = 0.f;
        if ((unsigned)gr < (unsigned)FH && (unsigned)gc < (unsigned)FW)
          v = feat[(size_t)(cib * 32 + ci) * HW + gr * FW + gc];
        unsigned short hh, mm, ll;
        split3(v, hh, mm, ll);
        int off = rr * 720 + cc * 40 + ci;
        flh[off] = hh; flm[off] = mm; fll[off] = ll;
      }
    }
    __syncthreads();
    const int ctg0 = cb * 8 + wv * 2;
    for (int kh = 0; kh < 3; ++kh) {
      for (int kw = 0; kw < 3; ++kw) {
        const int tap = kh * 3 + kw;
        const int abase = ((ctg0 * 9 + tap) * 8 + cib) * 64 + L;
        const int abase1 = abase + 9 * 8 * 64;
        short8 ah0 = ((const short8*)AW_h)[abase];
        short8 am0 = ((const short8*)AW_m)[abase];
        short8 al0 = ((const short8*)AW_l)[abase];
        short8 ah1 = ((const short8*)AW_h)[abase1];
        short8 am1 = ((const short8*)AW_m)[abase1];
        short8 al1 = ((const short8*)AW_l)[abase1];
        const int cbase = (nl + kw) * 40 + q * 8;
#pragma unroll
        for (int r = 0; r < 8; ++r) {
          const int off = (r + kh) * 720 + cbase;
          short8 bh = *(const short8*)(flh + off);
          short8 bm = *(const short8*)(flm + off);
          short8 bl = *(const short8*)(fll + off);
          acc[0][r] = MFMA16(ah0, bh, acc[0][r]);
          acc[0][r] = MFMA16(ah0, bm, acc[0][r]);
          acc[0][r] = MFMA16(am0, bh, acc[0][r]);
          acc[0][r] = MFMA16(ah0, bl, acc[0][r]);
          acc[0][r] = MFMA16(am0, bm, acc[0][r]);
          acc[0][r] = MFMA16(al0, bh, acc[0][r]);
          acc[1][r] = MFMA16(ah1, bh, acc[1][r]);
          acc[1][r] = MFMA16(ah1, bm, acc[1][r]);
          acc[1][r] = MFMA16(am1, bh, acc[1][r]);
          acc[1][r] = MFMA16(ah1, bl, acc[1][r]);
          acc[1][r] = MFMA16(am1, bm, acc[1][r]);
          acc[1][r] = MFMA16(al1, bh, acc[1][r]);
        }
      }
    }
  }

  // ---- epilogue ----
  float bv[2][4];
#pragma unroll
  for (int ct = 0; ct < 2; ++ct)
#pragma unroll
    for (int i = 0; i < 4; ++i)
      bv[ct][i] = bias[cb * 128 + (wv * 2 + ct) * 16 + q * 4 + i];

  unsigned short* xlh = smem;           // [64 px][136 co-pad] u16
  unsigned short* xlm = smem + 8704;
  unsigned short* xll = smem + 17408;

  for (int hp = 0; hp < 2; ++hp) {
    __syncthreads();
#pragma unroll
    for (int ct = 0; ct < 2; ++ct) {
#pragma unroll
      for (int rr = 0; rr < 4; ++rr) {
        int r = hp * 4 + rr;
        unsigned short xh[4], xm[4], xl_[4];
#pragma unroll
        for (int i = 0; i < 4; ++i) {
          float xv = fmaxf(acc[ct][r][i] + bv[ct][i], 0.f);
          split3(xv, xh[i], xm[i], xl_[i]);
        }
        int px_l = rr * 16 + nl;
        int co_l = (wv * 2 + ct) * 16 + q * 4;
        uint2 ph, pm, pl;
        ph.x = xh[0] | (xh[1] << 16); ph.y = xh[2] | (xh[3] << 16);
        pm.x = xm[0] | (xm[1] << 16); pm.y = xm[2] | (xm[3] << 16);
        pl.x = xl_[0] | (xl_[1] << 16); pl.y = xl_[2] | (xl_[3] << 16);
        *(uint2*)(xlh + px_l * 136 + co_l) = ph;
        *(uint2*)(xlm + px_l * 136 + co_l) = pm;
        *(uint2*)(xll + px_l * 136 + co_l) = pl;
      }
    }
    __syncthreads();
    floatx4 ha[3];
#pragma unroll
    for (int mt = 0; mt < 3; ++mt) ha[mt] = (floatx4)0.f;
    for (int ks = 0; ks < 4; ++ks) {
      const int off = (wv * 16 + nl) * 136 + ks * 32 + q * 8;
      short8 bh = *(const short8*)(xlh + off);
      short8 bm = *(const short8*)(xlm + off);
      short8 bl = *(const short8*)(xll + off);
#pragma unroll
      for (int mt = 0; mt < 3; ++mt) {
        const int hb = (mt * 8 + cb * 4 + ks) * 64 + L;
        short8 hh = ((const short8*)HwF_h)[hb];
        short8 hm = ((const short8*)HwF_m)[hb];
        short8 hl = ((const short8*)HwF_l)[hb];
        ha[mt] = MFMA16(hh, bh, ha[mt]);
        ha[mt] = MFMA16(hh, bm, ha[mt]);
        ha[mt] = MFMA16(hm, bh, ha[mt]);
        ha[mt] = MFMA16(hh, bl, ha[mt]);
        ha[mt] = MFMA16(hm, bm, ha[mt]);
        ha[mt] = MFMA16(hl, bh, ha[mt]);
      }
    }
    int gr = h0 + hp * 4 + wv;
    int gc = w0 + nl;
    if (gc < FW) {
#pragma unroll
      for (int mt = 0; mt < 3; ++mt)
#pragma unroll
        for (int i = 0; i < 4; ++i) {
          int head = mt * 16 + q * 4 + i;
          if (head < 45)
            atomicAdd(&logits[(size_t)(gr * FW + gc) * 45 + head], ha[mt][i]);
        }
    }
  }
}

// =====================================================================
// finalize — bias + anchors + deltas + sigmoid from logits
// =====================================================================
__global__ __launch_bounds__(256) void finalize_kernel(
    const float* __restrict__ logits, const float* __restrict__ cls_b,
    const float* __restrict__ reg_b, float* __restrict__ prop,
    float* __restrict__ score) {
  int px = blockIdx.x * 256 + threadIdx.x;
  if (px >= HW) return;
  float A[45];
  const float* lp = logits + (size_t)px * 45;
#pragma unroll
  for (int i = 0; i < 45; ++i) A[i] = lp[i];
  const float scv[3] = {128.f, 256.f, 512.f};
  const float arv[3] = {0.5f, 1.f, 2.f};
  float sx = (float)(px % FW) * 8.0f;
  float sy = (float)(px / FW) * 8.0f;
#pragma unroll
  for (int a = 0; a < NUM_A; ++a) {
    int ai = a / 3, si = a % 3;
    float hr = sqrtf(arv[ai]);
    float wr = 1.0f / hr;
    float rw = nearbyintf(wr * scv[si] * 0.5f);
    float rh = nearbyintf(hr * scv[si] * 0.5f);
    float ax0 = sx - rw, ay0 = sy - rh, ax1 = sx + rw, ay1 = sy + rh;
    float aw = ax1 - ax0, ah = ay1 - ay0;
    float cx = ax0 + 0.5f * aw, cy = ay0 + 0.5f * ah;
    float dx = A[9 + a * 4 + 0] + reg_b[a * 4 + 0];
    float dy = A[9 + a * 4 + 1] + reg_b[a * 4 + 1];
    float dw = fminf(A[9 + a * 4 + 2] + reg_b[a * 4 + 2], BBOX_CLIP_F);
    float dh = fminf(A[9 + a * 4 + 3] + reg_b[a * 4 + 3], BBOX_CLIP_F);
    float pcx = dx * aw + cx;
    float pcy = dy * ah + cy;
    float pw = expf(dw) * aw;
    float ph = expf(dh) * ah;
    size_t base = (size_t)(px * NUM_A + a) * 4;
    prop[base + 0] = pcx - 0.5f * pw;
    prop[base + 1] = pcy - 0.5f * ph;
    prop[base + 2] = pcx + 0.5f * pw;
    prop[base + 3] = pcy + 0.5f * ph;
    float lg = A[a] + cls_b[a];
    score[px * NUM_A + a] = 1.0f / (1.0f + expf(-lg));
  }
}

// =====================================================================
// Radix select (4 passes of 8 bits) for exact top-2000 threshold
// =====================================================================
__global__ __launch_bounds__(256) void hist_kernel(
    const float* __restrict__ score, unsigned int* __restrict__ hist,
    const unsigned int* __restrict__ state, int pass) {
  __shared__ unsigned int h[256];
  int t = threadIdx.x;
  h[t] = 0;
  __syncthreads();
  unsigned int prefix = (pass == 0) ? 0u : state[0];
  int shift = 24 - 8 * pass;
  for (int i = blockIdx.x * 256 + t; i < NANCH; i += gridDim.x * 256) {
    unsigned int key = __float_as_uint(score[i]);
    bool m = (pass == 0) || ((key >> (32 - 8 * pass)) == prefix);
    if (m) atomicAdd(&h[(key >> shift) & 255u], 1u);
  }
  __syncthreads();
  if (h[t]) atomicAdd(&hist[t], h[t]);
}

__global__ __launch_bounds__(256) void scan_kernel(
    unsigned int* __restrict__ hist, unsigned int* __restrict__ state, int pass) {
  __shared__ unsigned int s0[256], s1[256];
  int t = threadIdx.x;
  unsigned int hv = hist[t];
  hist[t] = 0u;
  s0[t] = hv;
  __syncthreads();
  unsigned int* A = s0;
  unsigned int* B = s1;
  for (int off = 1; off < 256; off <<= 1) {
    B[t] = A[t] + ((t + off < 256) ? A[t + off] : 0u);
    __syncthreads();
    unsigned int* tmp = A; A = B; B = tmp;
  }
  unsigned int prefix = (pass == 0) ? 0u : state[0];
  unsigned int rem = (pass == 0) ? (unsigned)PRE_K : state[1];
  unsigned int suf = A[t];
  unsigned int sufn = (t < 255) ? A[t + 1] : 0u;
  if (suf >= rem && sufn < rem) {
    state[0] = (prefix << 8) | (unsigned int)t;
    state[1] = rem - sufn;
  }
}

__global__ __launch_bounds__(256) void collect_kernel(
    const float* __restrict__ score, unsigned int* __restrict__ state,
    unsigned long long* __restrict__ cand) {
  unsigned int T = state[0];
  for (int i = blockIdx.x * 256 + threadIdx.x; i < NANCH; i += gridDim.x * 256) {
    unsigned int key = __float_as_uint(score[i]);
    if (key >= T) {
      unsigned int pos = atomicAdd(&state[4], 1u);
      if (pos < 4096u)
        cand[pos] = ((unsigned long long)key << 32) |
                    (unsigned long long)(~(unsigned int)i);
    }
  }
}

// =====================================================================
// Bitonic sort + gather + clip + valid + stable partition
// =====================================================================
__global__ __launch_bounds__(1024) void sort_gather(
    const unsigned long long* __restrict__ cand,
    const unsigned int* __restrict__ state, const float* __restrict__ prop,
    const float* __restrict__ score, float* __restrict__ boxes_s,
    float* __restrict__ sc_s) {
  __shared__ unsigned long long sk[4096];
  int t = threadIdx.x;
  unsigned int cnt = state[4];
  if (cnt > 4096u) cnt = 4096u;
  for (int e = t; e < 4096; e += 1024) sk[e] = (e < (int)cnt) ? cand[e] : 0ull;
  __syncthreads();
  for (int k = 2; k <= 4096; k <<= 1) {
    for (int j = k >> 1; j > 0; j >>= 1) {
      for (int i = t; i < 4096; i += 1024) {
        int l = i ^ j;
        if (l > i) {
          unsigned long long a = sk[i], bb = sk[l];
          bool up = ((i & k) == 0);
          bool sw = up ? (a < bb) : (a > bb);
          if (sw) { sk[i] = bb; sk[l] = a; }
        }
      }
      __syncthreads();
    }
  }
  float bx[2][4];
  float sc2[2] = {-1.f, -1.f};
  bool valid2[2] = {false, false};
#pragma unroll
  for (int s = 0; s < 2; ++s) {
    int i = t + s * 1024;
    bx[s][0] = bx[s][1] = bx[s][2] = bx[s][3] = 0.f;
    if (i < PRE_K) {
      unsigned long long v = sk[i];
      unsigned int idx = ~(unsigned int)(v & 0xFFFFFFFFull);
      float4 p = *(const float4*)(prop + (size_t)idx * 4);
      float x0 = fminf(fmaxf(p.x, 0.f), IMG_SZ);
      float y0 = fminf(fmaxf(p.y, 0.f), IMG_SZ);
      float x1 = fminf(fmaxf(p.z, 0.f), IMG_SZ);
      float y1 = fminf(fmaxf(p.w, 0.f), IMG_SZ);
      bool valid = (x1 - x0 >= MIN_SZ) && (y1 - y0 >= MIN_SZ);
      bx[s][0] = x0; bx[s][1] = y0; bx[s][2] = x1; bx[s][3] = y1;
      valid2[s] = valid;
      sc2[s] = valid ? score[idx] : -1.0f;
    }
  }
  __syncthreads();
  int* A = (int*)sk;
  int* B = A + 2048;
#pragma unroll
  for (int s = 0; s < 2; ++s) {
    int i = t + s * 1024;
    A[i] = (i < PRE_K && valid2[s]) ? 1 : 0;
  }
  __syncthreads();
  for (int off = 1; off < 2048; off <<= 1) {
#pragma unroll
    for (int s = 0; s < 2; ++s) {
      int i = t + s * 1024;
      B[i] = A[i] + ((i >= off) ? A[i - off] : 0);
    }
    __syncthreads();
    int* tmp = A; A = B; B = tmp;
  }
  int total = A[2047];
#pragma unroll
  for (int s = 0; s < 2; ++s) {
    int i = t + s * 1024;
    if (i < PRE_K) {
      int inc = A[i];
      int pos = valid2[s] ? (inc - 1) : (total + (i - inc));
      boxes_s[pos * 4 + 0] = bx[s][0];
      boxes_s[pos * 4 + 1] = bx[s][1];
      boxes_s[pos * 4 + 2] = bx[s][2];
      boxes_s[pos * 4 + 3] = bx[s][3];
      sc_s[pos] = sc2[s];
    }
  }
}

// =====================================================================
// IoU suppression bitmask (+ coalesced diag words)
// =====================================================================
__global__ __launch_bounds__(64) void iou_kernel(
    const float* __restrict__ boxes_s, unsigned long long* __restrict__ mask,
    unsigned long long* __restrict__ diag) {
  int bi = blockIdx.y, bj = blockIdx.x;
  int t = threadIdx.x;
  __shared__ float4 cb[64];
  int jc = bj * 64 + t;
  float4 z; z.x = z.y = z.z = z.w = 0.f;
  cb[t] = (jc < PRE_K) ? *(const float4*)(boxes_s + (size_t)jc * 4) : z;
  __syncthreads();
  int i = bi * 64 + t;
  if (i >= PRE_K) return;
  float4 a = *(const float4*)(boxes_s + (size_t)i * 4);
  float areaA = (a.z - a.x) * (a.w - a.y);
  unsigned long long bits = 0ull;
  for (int jj = 0; jj < 64; ++jj) {
    int j = bj * 64 + jj;
    if (j < PRE_K && j > i) {
      float4 b = cb[jj];
      float areaB = (b.z - b.x) * (b.w - b.y);
      float ltx = fmaxf(a.x, b.x), lty = fmaxf(a.y, b.y);
      float rbx = fminf(a.z, b.z), rby = fminf(a.w, b.w);
      float w = fmaxf(rbx - ltx, 0.f), h = fmaxf(rby - lty, 0.f);
      float inter = w * h;
      float iou = inter / (areaA + areaB - inter + 1e-9f);
      if (iou > NMS_TH) bits |= (1ull << jj);
    }
  }
  mask[(size_t)i * 32 + bj] = bits;
  if (bi == bj) diag[i] = bits;
}

// =====================================================================
// Block-resolved sequential NMS + final compaction to d_out.
// ONE block.  32 candidate-blocks of 64.  Per block: coalesced diag load,
// 64-step in-register shfl resolve, then batched push-apply: 8 alive rows
// per iteration via 4 independent 64-lane loads (2 rows/load, hi half
// folded with shfl).  Early-terminate once kept >= OUT_K (later blocks
// cannot affect the first 1000 outputs).  Semantics == greedy scan.
// =====================================================================
__global__ __launch_bounds__(256) void nms_out_kernel(
    const float* __restrict__ boxes_s, const float* __restrict__ sc_s,
    const unsigned long long* __restrict__ mask,
    const unsigned long long* __restrict__ diag, float* __restrict__ out) {
  int t = threadIdx.x;
  for (int e = t; e < (OUT_K * 4 + OUT_K); e += 256) out[e] = 0.f;
  __shared__ unsigned long long keepw[32];
  if (t < 64) {
    unsigned long long removed = 0ull;  // lanes 0..31 own word t
    if (t < 32) {
      keepw[t] = 0ull;
#pragma unroll
      for (int k = 0; k < 64; ++k) {
        int idx = t * 64 + k;
        if (idx >= PRE_K || sc_s[idx] < 0.f) removed |= (1ull << k);
      }
    }
    const int w = t & 31;
    const int half = t >> 5;
    unsigned int kept = 0;
    for (int b = 0; b < 32; ++b) {
      unsigned long long d = diag[b * 64 + t];  // coalesced 512B
      unsigned long long dead = __shfl(removed, b);
      unsigned long long alive = 0ull;
#pragma unroll
      for (int k = 0; k < 64; ++k) {
        unsigned long long dk = __shfl(d, k);
        if (!((dead >> k) & 1ull)) {
          alive |= (1ull << k);
          dead |= dk;
        }
      }
      if (t == 0) keepw[b] = alive;
      kept += (unsigned)__popcll(alive);
      if (kept >= (unsigned)OUT_K || b == 31) break;
      // push-apply: OR alive rows' mask into future words; 8 rows/iter.
      unsigned long long am = alive;
      const long long rb = (long long)b * 64;
      while (am) {
        int k0 = __ffsll(am) - 1; am &= am - 1;
        int k1 = k0, k2 = k0, k3 = k0, k4 = k0, k5 = k0, k6 = k0, k7 = k0;
        if (am) { k1 = __ffsll(am) - 1; am &= am - 1; }
        if (am) { k2 = __ffsll(am) - 1; am &= am - 1; }
        if (am) { k3 = __ffsll(am) - 1; am &= am - 1; }
        if (am) { k4 = __ffsll(am) - 1; am &= am - 1; }
        if (am) { k5 = __ffsll(am) - 1; am &= am - 1; }
        if (am) { k6 = __ffsll(am) - 1; am &= am - 1; }
        if (am) { k7 = __ffsll(am) - 1; am &= am - 1; }
        unsigned long long v0 = mask[(size_t)(rb + (half ? k1 : k0)) * 32 + w];
        unsigned long long v1 = mask[(size_t)(rb + (half ? k3 : k2)) * 32 + w];
        unsigned long long v2 = mask[(size_t)(rb + (half ? k5 : k4)) * 32 + w];
        unsigned long long v3 = mask[(size_t)(rb + (half ? k7 : k6)) * 32 + w];
        unsigned long long vv = v0 | v1 | v2 | v3;
        unsigned long long hv = __shfl(vv, w + 32);
        if (t < 32) removed |= vv | hv;
      }
    }
  }
  __syncthreads();
  __shared__ unsigned int wbase[32];
  if (t == 0) {
    unsigned int s = 0;
    for (int k = 0; k < 32; ++k) {
      wbase[k] = s;
      s += (unsigned)__popcll(keepw[k]);
    }
  }
  __syncthreads();
  for (int i = t; i < PRE_K; i += 256) {
    unsigned long long w2 = keepw[i >> 6];
    if ((w2 >> (i & 63)) & 1ull) {
      unsigned int pos =
          wbase[i >> 6] +
          (unsigned)__popcll(w2 & ((1ull << (i & 63)) - 1ull));
      if (pos < OUT_K) {
        out[pos * 4 + 0] = boxes_s[i * 4 + 0];
        out[pos * 4 + 1] = boxes_s[i * 4 + 1];
        out[pos * 4 + 2] = boxes_s[i * 4 + 2];
        out[pos * 4 + 3] = boxes_s[i * 4 + 3];
        out[OUT_K * 4 + pos] = sc_s[i];
      }
    }
  }
}

// =====================================================================
extern "C" void kernel_launch(void* const* d_in, const int* in_sizes, int n_in,
                              void* d_out, int out_size, void* d_ws,
                              size_t ws_size, hipStream_t stream) {
  const float* feat = (const float*)d_in[1];
  const float* convw = (const float*)d_in[2];
  const float* convb = (const float*)d_in[3];
  const float* clsw = (const float*)d_in[4];
  const float* clsb = (const float*)d_in[5];
  const float* regw = (const float*)d_in[6];
  const float* regb = (const float*)d_in[7];

  char* ws = (char*)d_ws;
  float* logits = (float*)(ws + OFF_LOGIT);
  unsigned int* hist = (unsigned int*)(ws + OFF_HIST);
  unsigned int* state = (unsigned int*)(ws + OFF_STATE);
  unsigned long long* cand = (unsigned long long*)(ws + OFF_CAND);
  float* boxes_s = (float*)(ws + OFF_BOXS);
  float* sc_s = (float*)(ws + OFF_SCS);
  unsigned long long* mask = (unsigned long long*)(ws + OFF_MASK);
  uint4* AW_h = (uint4*)(ws + OFF_AWH);
  uint4* AW_m = (uint4*)(ws + OFF_AWM);
  uint4* AW_l = (uint4*)(ws + OFF_AWL);
  uint4* HwF_h = (uint4*)(ws + OFF_HWH);
  uint4* HwF_m = (uint4*)(ws + OFF_HWM);
  uint4* HwF_l = (uint4*)(ws + OFF_HWL);
  float* prop = (float*)(ws + OFF_PROP);
  float* score = (float*)(ws + OFF_SCORE);
  unsigned long long* diag = (unsigned long long*)(ws + OFF_DIAG);
  float* out = (float*)d_out;

  // zero logits + hist + state (contiguous prefix)
  hipMemsetAsync(ws, 0, OFF_STATE + 64, stream);

  prep_weights<<<294, 256, 0, stream>>>(convw, clsw, regw, AW_h, AW_m, AW_l,
                                        HwF_h, HwF_m, HwF_l);
  conv_mfma<<<dim3(13, 25, 2), 256, 0, stream>>>(feat, AW_h, AW_m, AW_l,
                                                 HwF_h, HwF_m, HwF_l, convb,
                                                 logits);
  finalize_kernel<<<157, 256, 0, stream>>>(logits, clsb, regb, prop, score);
  for (int p = 0; p < 4; ++p) {
    hist_kernel<<<256, 256, 0, stream>>>(score, hist, state, p);
    scan_kernel<<<1, 256, 0, stream>>>(hist, state, p);
  }
  collect_kernel<<<256, 256, 0, stream>>>(score, state, cand);
  sort_gather<<<1, 1024, 0, stream>>>(cand, state, prop, score, boxes_s, sc_s);
  iou_kernel<<<dim3(32, 32), 64, 0, stream>>>(boxes_s, mask, diag);
  nms_out_kernel<<<1, 256, 0, stream>>>(boxes_s, sc_s, mask, diag, out);
}